// Round 4
// baseline (1809.904 us; speedup 1.0000x reference)
//
#include <hip/hip_runtime.h>
#include <hip/hip_bf16.h>
#include <math.h>

typedef __attribute__((ext_vector_type(4))) float f32x4;
typedef __attribute__((ext_vector_type(8))) short s16x8;
typedef unsigned short ushort_t;

// ---------- bf16 bit helpers (RNE) ----------
__device__ __forceinline__ float bfbits2f(unsigned short u) {
  unsigned int x = ((unsigned int)u) << 16;
  return __builtin_bit_cast(float, x);
}
__device__ __forceinline__ unsigned short f2bfbits(float f) {
  unsigned int x = __builtin_bit_cast(unsigned int, f);
  unsigned int r = x + 0x7fffu + ((x >> 16) & 1u);
  return (unsigned short)(r >> 16);
}

// ---------- activation enum ----------
#define ACT_NONE 0
#define ACT_RELU 1
#define ACT_GELU 2
#define ACT_SIGM 3

// =====================================================================
// Generic bf16 MFMA GEMM, NT layout: C[M,N] = act(alpha*A[M,K]*B[N,K]^T + bias + res)
// A row-major lda, B row-major [N][K] ldb. 128x128 tile, BK=64, 256 thr (4 waves 2x2).
// LDS XOR-swizzled (T2) on 16B granules (reg-staged, so swizzle is legal).
// =====================================================================
template<int ACT, bool OBF, bool BIAS, bool RES>
__global__ __launch_bounds__(256) void gemm_bf16(
    const ushort_t* __restrict__ A, const ushort_t* __restrict__ B,
    void* __restrict__ C, const float* __restrict__ bias, float bscale,
    const float* __restrict__ res,
    int K, int lda, int ldb, int ldc, float alpha, int nz2,
    long long sA1, long long sA2, long long sB1, long long sB2,
    long long sC1, long long sC2)
{
  const int z = blockIdx.z;
  const int z1 = z / nz2, z2 = z % nz2;
  const ushort_t* Ab = A + z1 * sA1 + z2 * sA2 + (long long)blockIdx.y * 128 * lda;
  const ushort_t* Bb = B + z1 * sB1 + z2 * sB2 + (long long)blockIdx.x * 128 * ldb;
  const long long coff = z1 * sC1 + z2 * sC2;

  __shared__ ushort_t As[128 * 64];
  __shared__ ushort_t Bs[128 * 64];

  const int tid = threadIdx.x;
  const int lane = tid & 63, wid = tid >> 6;
  const int wr = wid >> 1, wc = wid & 1;
  const int lr = lane & 15, lk = lane >> 4;

  const int r0 = tid >> 3, c8 = tid & 7;  // staging: row = it*32 + r0, col-granule c8

  f32x4 acc[4][4];
#pragma unroll
  for (int m = 0; m < 4; ++m)
#pragma unroll
    for (int n = 0; n < 4; ++n) {
      acc[m][n][0] = 0.f; acc[m][n][1] = 0.f; acc[m][n][2] = 0.f; acc[m][n][3] = 0.f;
    }

  const int nk = K >> 6;
  for (int kt = 0; kt < nk; ++kt) {
    const ushort_t* Ak = Ab + kt * 64;
    const ushort_t* Bk = Bb + kt * 64;
    s16x8 ra[4], rb[4];
#pragma unroll
    for (int it = 0; it < 4; ++it) {
      int row = it * 32 + r0;
      ra[it] = *(const s16x8*)(Ak + (long long)row * lda + c8 * 8);
      rb[it] = *(const s16x8*)(Bk + (long long)row * ldb + c8 * 8);
    }
    __syncthreads();  // protect previous iteration's LDS reads
#pragma unroll
    for (int it = 0; it < 4; ++it) {
      int row = it * 32 + r0;
      int sc = (c8 ^ (row & 7)) << 3;
      *(s16x8*)(&As[row * 64 + sc]) = ra[it];
      *(s16x8*)(&Bs[row * 64 + sc]) = rb[it];
    }
    __syncthreads();
#pragma unroll
    for (int kk = 0; kk < 2; ++kk) {
      s16x8 af[4], bv[4];
#pragma unroll
      for (int m = 0; m < 4; ++m) {
        int row = wr * 64 + m * 16 + lr;
        int cc = ((kk * 4 + lk) ^ (row & 7)) << 3;
        af[m] = *(const s16x8*)(&As[row * 64 + cc]);
      }
#pragma unroll
      for (int n = 0; n < 4; ++n) {
        int row = wc * 64 + n * 16 + lr;
        int cc = ((kk * 4 + lk) ^ (row & 7)) << 3;
        bv[n] = *(const s16x8*)(&Bs[row * 64 + cc]);
      }
#pragma unroll
      for (int m = 0; m < 4; ++m)
#pragma unroll
        for (int n = 0; n < 4; ++n)
          acc[m][n] = __builtin_amdgcn_mfma_f32_16x16x32_bf16(af[m], bv[n], acc[m][n], 0, 0, 0);
    }
  }

  // epilogue: D[(lane>>4)*4 + r][lane&15]
  const long long row0 = (long long)blockIdx.y * 128 + wr * 64 + lk * 4;
  const int col0 = blockIdx.x * 128 + wc * 64 + lr;
#pragma unroll
  for (int m = 0; m < 4; ++m)
#pragma unroll
    for (int n = 0; n < 4; ++n)
#pragma unroll
      for (int r = 0; r < 4; ++r) {
        long long row = row0 + m * 16 + r;
        int col = col0 + n * 16;
        float v = acc[m][n][r] * alpha;
        if (BIAS) v += bias[col] * bscale;
        if (RES) v += res[coff + row * ldc + col];
        if (ACT == ACT_RELU) v = fmaxf(v, 0.f);
        else if (ACT == ACT_GELU) v = 0.5f * v * (1.f + erff(v * 0.70710678118654752f));
        else if (ACT == ACT_SIGM) v = 1.f / (1.f + expf(-v));
        if (OBF) ((ushort_t*)C)[coff + row * ldc + col] = f2bfbits(v);
        else ((float*)C)[coff + row * ldc + col] = v;
      }
}

// =====================================================================
// LayerNorm: fp32 in (rows x 512) -> bf16 out
// =====================================================================
__global__ __launch_bounds__(256) void ln_kernel(const float* __restrict__ h,
                                                 const float* __restrict__ g,
                                                 const float* __restrict__ b,
                                                 ushort_t* __restrict__ out)
{
  const int D = 512;
  long long row = blockIdx.x;
  const float* x = h + row * D;
  int t = threadIdx.x;
  float v0 = x[t], v1 = x[t + 256];
  __shared__ float rs[256], rss[256];
  rs[t] = v0 + v1; rss[t] = v0 * v0 + v1 * v1;
  __syncthreads();
  for (int o = 128; o > 0; o >>= 1) {
    if (t < o) { rs[t] += rs[t + o]; rss[t] += rss[t + o]; }
    __syncthreads();
  }
  float mean = rs[0] * (1.f / D);
  float var = rss[0] * (1.f / D) - mean * mean;
  float inv = rsqrtf(var + 1e-5f);
  out[row * D + t] = f2bfbits((v0 - mean) * inv * g[t] + b[t]);
  out[row * D + t + 256] = f2bfbits((v1 - mean) * inv * g[t + 256] + b[t + 256]);
}

// =====================================================================
// In-place row softmax on bf16 scores, row length 2048
// =====================================================================
__global__ __launch_bounds__(256) void softmax_kernel(ushort_t* __restrict__ S)
{
  long long row = blockIdx.x;
  ushort_t* p = S + row * 2048;
  int t = threadIdx.x;
  s16x8 raw = *(const s16x8*)(p + t * 8);
  float v[8];
#pragma unroll
  for (int j = 0; j < 8; ++j) v[j] = bfbits2f((unsigned short)raw[j]);
  float m = v[0];
#pragma unroll
  for (int j = 1; j < 8; ++j) m = fmaxf(m, v[j]);
  __shared__ float red[256];
  red[t] = m; __syncthreads();
  for (int o = 128; o > 0; o >>= 1) {
    if (t < o) red[t] = fmaxf(red[t], red[t + o]);
    __syncthreads();
  }
  m = red[0];
  __syncthreads();
  float s = 0.f;
#pragma unroll
  for (int j = 0; j < 8; ++j) { v[j] = expf(v[j] - m); s += v[j]; }
  red[t] = s; __syncthreads();
  for (int o = 128; o > 0; o >>= 1) {
    if (t < o) red[t] += red[t + o];
    __syncthreads();
  }
  float inv = 1.f / red[0];
  s16x8 outv;
#pragma unroll
  for (int j = 0; j < 8; ++j) outv[j] = (short)f2bfbits(v[j] * inv);
  *(s16x8*)(p + t * 8) = outv;
}

// =====================================================================
// x (8,2048,1024) fp32 -> zero-padded bf16 [8][2050][1024]
// =====================================================================
__global__ __launch_bounds__(256) void build_xpad(const float* __restrict__ x,
                                                  ushort_t* __restrict__ xp)
{
  long long idx = (long long)blockIdx.x * 256 + threadIdx.x;  // 8*2050*1024
  int c = (int)(idx % 1024);
  long long t = idx / 1024;
  int r = (int)(t % 2050);
  int b = (int)(t / 2050);
  float v = (r == 0 || r == 2049) ? 0.f : x[((long long)b * 2048 + (r - 1)) * 1024 + c];
  xp[idx] = f2bfbits(v);
}

// =====================================================================
// A2[i][j] = exp(-|i-j|/e) / sum_m exp(-|j-m|/e)  (closed-form column sums)
// =====================================================================
__global__ __launch_bounds__(256) void build_a2(ushort_t* __restrict__ A2)
{
  const int n = 2048;
  long long idx = (long long)blockIdx.x * 256 + threadIdx.x;
  int i = (int)(idx / n), j = (int)(idx % n);
  const float inv_e = 0.36787944117144233f;
  float w = expf(-fabsf((float)(i - j)) * inv_e);
  float r = expf(-inv_e);
  float geo = r / (1.f - r);
  float s = 1.f + geo * (1.f - expf(-inv_e * (float)j))
               + geo * (1.f - expf(-inv_e * (float)(n - 1 - j)));
  A2[idx] = f2bfbits(w / s);
}

// =====================================================================
// transpose + cast fp32 (R x C) -> bf16 (C x R), batched
// FIXED (round 3): write tile[tx][ty+i*8] — previous version swapped
// block coords but not intra-tile coords (block-permutation, not transpose).
// =====================================================================
__global__ __launch_bounds__(256) void tr_cast(const float* __restrict__ src0,
                                               ushort_t* __restrict__ dst0,
                                               int R, int C, long long ss, long long ds)
{
  const float* src = src0 + (long long)blockIdx.z * ss;
  ushort_t* dst = dst0 + (long long)blockIdx.z * ds;
  __shared__ float tile[32][33];
  int tx = threadIdx.x, ty = threadIdx.y;
#pragma unroll
  for (int i = 0; i < 4; ++i) {
    int r = blockIdx.y * 32 + ty + i * 8;
    int c = blockIdx.x * 32 + tx;
    tile[ty + i * 8][tx] = src[(long long)r * C + c];
  }
  __syncthreads();
#pragma unroll
  for (int i = 0; i < 4; ++i) {
    int rr = blockIdx.x * 32 + ty + i * 8;  // dst row (= src col)
    int cc = blockIdx.y * 32 + tx;          // dst col (= src row)
    dst[(long long)rr * R + cc] = f2bfbits(tile[tx][ty + i * 8]);
  }
}

// =====================================================================
// Per-(b,h) transpose of V/T slices of qkvt: out[p][d][n] (bf16)
// =====================================================================
__global__ __launch_bounds__(256) void tr_pair(const ushort_t* __restrict__ qkvt,
                                               ushort_t* __restrict__ out, int coloff)
{
  int p = blockIdx.z;
  int b = p >> 2, hh = p & 3;
  const ushort_t* src = qkvt + ((long long)b * 2048) * 2048 + coloff + hh * 128;
  ushort_t* dst = out + (long long)p * 128 * 2048;
  __shared__ ushort_t tile[32][33];
  int tx = threadIdx.x, ty = threadIdx.y;
  int n0 = blockIdx.x * 32, d0 = blockIdx.y * 32;
#pragma unroll
  for (int i = 0; i < 4; ++i)
    tile[ty + i * 8][tx] = src[(long long)(n0 + ty + i * 8) * 2048 + d0 + tx];
  __syncthreads();
#pragma unroll
  for (int i = 0; i < 4; ++i)
    dst[(long long)(d0 + ty + i * 8) * 2048 + n0 + tx] = tile[tx][ty + i * 8];
}

// =====================================================================
// memory banks: memc[128][512] = [amem(60); 0; nmem(60); 0], memTc[512][128] = memc^T
// =====================================================================
__global__ __launch_bounds__(256) void build_mem(const float* __restrict__ amem,
                                                 const float* __restrict__ nmem,
                                                 ushort_t* __restrict__ memc,
                                                 ushort_t* __restrict__ memTc)
{
  int idx = blockIdx.x * 256 + threadIdx.x;  // 128*512
  int r = idx / 512, d = idx % 512;
  float v = 0.f;
  if (r < 60) v = amem[r * 512 + d];
  else if (r >= 64 && r < 124) v = nmem[(r - 64) * 512 + d];
  unsigned short u = f2bfbits(v);
  memc[idx] = u;
  memTc[d * 128 + r] = u;
}

// =====================================================================
// fp32 rows -> bf16 into strided dst (used for h -> z[:, :512])
// =====================================================================
__global__ __launch_bounds__(256) void cast_rows(const float* __restrict__ src,
                                                 ushort_t* __restrict__ dst,
                                                 int cols, int ldd)
{
  long long idx = (long long)blockIdx.x * 256 + threadIdx.x;
  long long r = idx / cols;
  int c = (int)(idx % cols);
  dst[r * ldd + c] = f2bfbits(src[idx]);
}

// =====================================================================
// final: out[row] = sigmoid( dot(relu_cls1[row], w2) + b2 )
// =====================================================================
__global__ __launch_bounds__(256) void cls2_kernel(const ushort_t* __restrict__ cls1,
                                                   const float* __restrict__ w2,
                                                   const float* __restrict__ b2,
                                                   float* __restrict__ out)
{
  int row = blockIdx.x * 4 + (threadIdx.x >> 6);
  int lane = threadIdx.x & 63;
  const ushort_t* rp = cls1 + (long long)row * 128;
  float v = bfbits2f(rp[lane]) * w2[lane] + bfbits2f(rp[lane + 64]) * w2[lane + 64];
#pragma unroll
  for (int m = 32; m > 0; m >>= 1) v += __shfl_xor(v, m, 64);
  if (lane == 0) out[row] = 1.f / (1.f + expf(-(v + b2[0])));
}

// =====================================================================
// host side
// =====================================================================
static inline void* carve(char*& p, size_t bytes) {
  void* r = (void*)p;
  p += (bytes + 255) & ~(size_t)255;
  return r;
}

template<int ACT, bool OBF, bool BIAS, bool RES>
static inline void gemm(hipStream_t st, const ushort_t* A, const ushort_t* B, void* C,
                        const float* bias, float bscale, const float* res,
                        int M, int N, int K, int lda, int ldb, int ldc, float alpha,
                        int Z, int nz2,
                        long long sA1, long long sA2, long long sB1, long long sB2,
                        long long sC1, long long sC2)
{
  dim3 grid(N / 128, M / 128, Z), blk(256, 1, 1);
  gemm_bf16<ACT, OBF, BIAS, RES><<<grid, blk, 0, st>>>(
      A, B, C, bias, bscale, res, K, lda, ldb, ldc, alpha, nz2,
      sA1, sA2, sB1, sB2, sC1, sC2);
}

extern "C" void kernel_launch(void* const* d_in, const int* in_sizes, int n_in,
                              void* d_out, int out_size, void* d_ws, size_t ws_size,
                              hipStream_t stream)
{
  (void)in_sizes; (void)n_in; (void)out_size; (void)ws_size;
  const float* x      = (const float*)d_in[0];
  const float* conv_w = (const float*)d_in[1];
  const float* conv_b = (const float*)d_in[2];
  const float* ln1_g  = (const float*)d_in[3];
  const float* ln1_b  = (const float*)d_in[4];
  const float* qkv_w  = (const float*)d_in[5];
  const float* out_w  = (const float*)d_in[6];
  const float* out_b  = (const float*)d_in[7];
  const float* ln2_g  = (const float*)d_in[8];
  const float* ln2_b  = (const float*)d_in[9];
  const float* ff_w1  = (const float*)d_in[10];
  const float* ff_b1  = (const float*)d_in[11];
  const float* ff_w2  = (const float*)d_in[12];
  const float* ff_b2  = (const float*)d_in[13];
  const float* amem   = (const float*)d_in[14];
  const float* nmem   = (const float*)d_in[15];
  const float* enc_w  = (const float*)d_in[16];
  const float* enc_b  = (const float*)d_in[17];
  const float* cls_w1 = (const float*)d_in[18];
  const float* cls_b1 = (const float*)d_in[19];
  const float* cls_w2 = (const float*)d_in[20];
  const float* cls_b2 = (const float*)d_in[21];
  float* outp = (float*)d_out;

  const long long M = 16384;       // 8 * 2048 rows
  const float att_scale = 0.08838834764831845f;   // 128^-0.5
  const float mem_scale = 0.04419417382415922f;   // 512^-0.5

  // ---- workspace layout with phase-based unions (~226 MB peak) ----
  char* p = (char*)d_ws;
  float*    h    = (float*)   carve(p, (size_t)M * 512 * 4);           // persistent
  ushort_t* A2b  = (ushort_t*)carve(p, (size_t)2048 * 2048 * 2);       // persistent
  // transposed weights (persistent)
  ushort_t* Wcat  = (ushort_t*)carve(p, (size_t)512 * 3072 * 2);
  ushort_t* qkvT  = (ushort_t*)carve(p, (size_t)2 * 2048 * 512 * 2);
  ushort_t* outT  = (ushort_t*)carve(p, (size_t)2 * 512 * 1024 * 2);
  ushort_t* f1T   = (ushort_t*)carve(p, (size_t)2 * 512 * 512 * 2);
  ushort_t* f2T   = (ushort_t*)carve(p, (size_t)2 * 512 * 512 * 2);
  ushort_t* encT  = (ushort_t*)carve(p, (size_t)512 * 512 * 2);
  ushort_t* c1T   = (ushort_t*)carve(p, (size_t)128 * 1024 * 2);
  ushort_t* memc  = (ushort_t*)carve(p, (size_t)128 * 512 * 2);
  ushort_t* memTc = (ushort_t*)carve(p, (size_t)512 * 128 * 2);
  // U1: xpad (conv) | Vt+Tt (attn) | ffb (ffn) | zb (final)  -- lifetime-disjoint
  char* U1 = (char*)carve(p, (size_t)8 * 2050 * 1024 * 2);             // 33.59 MB
  ushort_t* xpad = (ushort_t*)U1;
  ushort_t* Vt   = (ushort_t*)U1;                                      // 16.78 MB
  ushort_t* Tt   = (ushort_t*)(U1 + (size_t)32 * 128 * 2048 * 2);      // 16.78 MB
  ushort_t* ffb  = (ushort_t*)U1;                                      // 16.78 MB
  ushort_t* zb   = (ushort_t*)U1;                                      // 33.55 MB
  // U2: qkvt (layers) | attb+m1b+cls1b (final)
  char* U2 = (char*)carve(p, (size_t)M * 2048 * 2);                    // 67.11 MB
  ushort_t* qkvt  = (ushort_t*)U2;
  ushort_t* attb  = (ushort_t*)U2;                                     // 4.19 MB
  ushort_t* m1b   = (ushort_t*)(U2 + (size_t)M * 128 * 2);             // 16.78 MB
  ushort_t* cls1b = (ushort_t*)(U2 + (size_t)M * 128 * 2 + (size_t)M * 512 * 2);
  // ob persistent within layer phase
  ushort_t* ob = (ushort_t*)carve(p, (size_t)M * 1024 * 2);            // 33.55 MB
  // U3: xn (LN out, dead during attention) | Sb (4-head score chunk)
  char* U3 = (char*)carve(p, (size_t)4 * 2048 * 2048 * 2);             // 33.55 MB
  ushort_t* xn = (ushort_t*)U3;
  ushort_t* Sb = (ushort_t*)U3;

  dim3 tb(32, 8, 1);

  // ---- prep: casts / transposes / constants ----
  build_xpad<<<(8 * 2050 * 1024) / 256, 256, 0, stream>>>(x, xpad);
  build_a2<<<(2048 * 2048) / 256, 256, 0, stream>>>(A2b);
  tr_cast<<<dim3(512 / 32, 3072 / 32, 1), tb, 0, stream>>>(conv_w, Wcat, 3072, 512, 0, 0);
  tr_cast<<<dim3(2048 / 32, 512 / 32, 2), tb, 0, stream>>>(qkv_w, qkvT, 512, 2048,
      (long long)512 * 2048, (long long)2048 * 512);
  tr_cast<<<dim3(512 / 32, 1024 / 32, 2), tb, 0, stream>>>(out_w, outT, 1024, 512,
      (long long)1024 * 512, (long long)512 * 1024);
  tr_cast<<<dim3(512 / 32, 512 / 32, 2), tb, 0, stream>>>(ff_w1, f1T, 512, 512,
      (long long)512 * 512, (long long)512 * 512);
  tr_cast<<<dim3(512 / 32, 512 / 32, 2), tb, 0, stream>>>(ff_w2, f2T, 512, 512,
      (long long)512 * 512, (long long)512 * 512);
  tr_cast<<<dim3(512 / 32, 512 / 32, 1), tb, 0, stream>>>(enc_w, encT, 512, 512, 0, 0);
  tr_cast<<<dim3(128 / 32, 1024 / 32, 1), tb, 0, stream>>>(cls_w1, c1T, 1024, 128, 0, 0);
  build_mem<<<256, 256, 0, stream>>>(amem, nmem, memc, memTc);

  // ---- conv1d as K=3072 GEMM over padded x, batched over b ----
  // (xpad in U1 is consumed here; U1 is reused afterwards)
  gemm<ACT_RELU, false, true, false>(stream, xpad, Wcat, h, conv_b, 1.f, nullptr,
      2048, 512, 3072, 1024, 3072, 512, 1.f,
      8, 8, 0, (long long)2050 * 1024, 0, 0, 0, (long long)2048 * 512);

  // ---- transformer layers ----
  for (int l = 0; l < 2; ++l) {
    ln_kernel<<<16384, 256, 0, stream>>>(h, ln1_g + l * 512, ln1_b + l * 512, xn);
    // qkvt = xn @ qkv_w[l]   (last read of xn before attention reuses U3 as Sb)
    gemm<ACT_NONE, true, false, false>(stream, xn, qkvT + (long long)l * 2048 * 512, qkvt,
        nullptr, 1.f, nullptr, 16384, 2048, 512, 512, 512, 2048, 1.f,
        1, 1, 0, 0, 0, 0, 0, 0);
    // V^T, T^T per (b,h)  (U1: xpad dead after conv / ffb dead after prev layer's ff2)
    tr_pair<<<dim3(64, 4, 32), tb, 0, stream>>>(qkvt, Vt, 1024);
    tr_pair<<<dim3(64, 4, 32), tb, 0, stream>>>(qkvt, Tt, 1536);
    // o2 = A2 @ t  -> ob cols [h*256+128, h*256+256)
    gemm<ACT_NONE, true, false, false>(stream, A2b, Tt, ob + 128, nullptr, 1.f, nullptr,
        2048, 128, 2048, 2048, 2048, 1024, 1.f,
        32, 4, 0, 0, (long long)4 * 128 * 2048, (long long)128 * 2048,
        (long long)2048 * 1024, 256);
    // attention: one batch (4 heads) per chunk; Sb = 33.5 MB in U3
    for (int bch = 0; bch < 8; ++bch) {
      const ushort_t* Qb = qkvt + (long long)bch * 2048 * 2048;
      const ushort_t* Kb = Qb + 512;
      // S = alpha * Q K^T   (Z=4 heads)
      gemm<ACT_NONE, true, false, false>(stream, Qb, Kb, Sb, nullptr, 1.f, nullptr,
          2048, 2048, 128, 2048, 2048, 2048, att_scale,
          4, 4, 0, 128, 0, 128,
          0, (long long)2048 * 2048);
      softmax_kernel<<<8192, 256, 0, stream>>>(Sb);
      // o1 = P @ V -> ob cols [h*256, h*256+128)
      gemm<ACT_NONE, true, false, false>(stream, Sb, Vt + (long long)bch * 4 * 128 * 2048,
          ob + (long long)bch * 2048 * 1024, nullptr, 1.f, nullptr,
          2048, 128, 2048, 2048, 2048, 1024, 1.f,
          4, 4, 0, (long long)2048 * 2048,
          0, (long long)128 * 2048,
          0, 256);
    }
    // h = ob @ out_w[l] + out_b + h
    gemm<ACT_NONE, false, true, true>(stream, ob, outT + (long long)l * 512 * 1024, h,
        out_b + l * 512, 1.f, h, 16384, 512, 1024, 1024, 1024, 512, 1.f,
        1, 1, 0, 0, 0, 0, 0, 0);
    ln_kernel<<<16384, 256, 0, stream>>>(h, ln2_g + l * 512, ln2_b + l * 512, xn);
    // ff1 (GELU)  (ffb in U1; Vt/Tt dead now)
    gemm<ACT_GELU, true, true, false>(stream, xn, f1T + (long long)l * 512 * 512, ffb,
        ff_b1 + l * 512, 1.f, nullptr, 16384, 512, 512, 512, 512, 512, 1.f,
        1, 1, 0, 0, 0, 0, 0, 0);
    // h = ff2 + h
    gemm<ACT_NONE, false, true, true>(stream, ffb, f2T + (long long)l * 512 * 512, h,
        ff_b2 + l * 512, 1.f, h, 16384, 512, 512, 512, 512, 512, 1.f,
        1, 1, 0, 0, 0, 0, 0, 0);
  }

  // ---- memory retrieval + classifier (qkvt dead -> attb/m1b/cls1b in U2; zb in U1) ----
  cast_rows<<<(16384 * 512) / 256, 256, 0, stream>>>(h, zb, 512, 1024);  // z[:, :512]
  // att = sigmoid(mscale * h @ [amem;0;nmem;0]^T)   (16384 x 128)
  gemm<ACT_SIGM, true, false, false>(stream, zb, memc, attb, nullptr, 1.f, nullptr,
      16384, 128, 512, 1024, 512, 128, mem_scale, 1, 1, 0, 0, 0, 0, 0, 0);
  // m1 = att @ [amem;0;nmem;0]   (padded rows zero -> exact)
  gemm<ACT_NONE, true, false, false>(stream, attb, memTc, m1b, nullptr, 1.f, nullptr,
      16384, 512, 128, 128, 128, 512, 1.f, 1, 1, 0, 0, 0, 0, 0, 0);
  // aug = m1 @ enc_w + 2*enc_b  -> z[:, 512:]
  gemm<ACT_NONE, true, true, false>(stream, m1b, encT, zb + 512, enc_b, 2.f, nullptr,
      16384, 512, 512, 512, 512, 1024, 1.f, 1, 1, 0, 0, 0, 0, 0, 0);
  // cls1 = relu(z @ cls_w1 + b1)
  gemm<ACT_RELU, true, true, false>(stream, zb, c1T, cls1b, cls_b1, 1.f, nullptr,
      16384, 128, 1024, 1024, 1024, 128, 1.f, 1, 1, 0, 0, 0, 0, 0, 0);
  // out = sigmoid(cls1 @ w2 + b2)
  cls2_kernel<<<4096, 256, 0, stream>>>(cls1b, cls_w2, cls_b2, outp);
}

// Round 5
// 1262.767 us; speedup vs baseline: 1.4333x; 1.4333x over previous
//
#include <hip/hip_runtime.h>
#include <hip/hip_bf16.h>
#include <math.h>

typedef __attribute__((ext_vector_type(4))) float f32x4;
typedef __attribute__((ext_vector_type(8))) short s16x8;
typedef unsigned short ushort_t;

// ---------- bf16 bit helpers (RNE) ----------
__device__ __forceinline__ float bfbits2f(unsigned short u) {
  unsigned int x = ((unsigned int)u) << 16;
  return __builtin_bit_cast(float, x);
}
__device__ __forceinline__ unsigned short f2bfbits(float f) {
  unsigned int x = __builtin_bit_cast(unsigned int, f);
  unsigned int r = x + 0x7fffu + ((x >> 16) & 1u);
  return (unsigned short)(r >> 16);
}

// ---------- activation enum ----------
#define ACT_NONE 0
#define ACT_RELU 1
#define ACT_GELU 2
#define ACT_SIGM 3

// =====================================================================
// Generic bf16 MFMA GEMM, NT layout: C[M,N] = act(alpha*A[M,K]*B[N,K]^T + bias + res)
// 128x128 tile, BK=64, 256 thr (4 waves 2x2). LDS XOR-swizzled (T2).
// =====================================================================
template<int ACT, bool OBF, bool BIAS, bool RES>
__global__ __launch_bounds__(256) void gemm_bf16(
    const ushort_t* __restrict__ A, const ushort_t* __restrict__ B,
    void* __restrict__ C, const float* __restrict__ bias, float bscale,
    const float* __restrict__ res,
    int K, int lda, int ldb, int ldc, float alpha, int nz2,
    long long sA1, long long sA2, long long sB1, long long sB2,
    long long sC1, long long sC2)
{
  const int z = blockIdx.z;
  const int z1 = z / nz2, z2 = z % nz2;
  const ushort_t* Ab = A + z1 * sA1 + z2 * sA2 + (long long)blockIdx.y * 128 * lda;
  const ushort_t* Bb = B + z1 * sB1 + z2 * sB2 + (long long)blockIdx.x * 128 * ldb;
  const long long coff = z1 * sC1 + z2 * sC2;

  __shared__ ushort_t As[128 * 64];
  __shared__ ushort_t Bs[128 * 64];

  const int tid = threadIdx.x;
  const int lane = tid & 63, wid = tid >> 6;
  const int wr = wid >> 1, wc = wid & 1;
  const int lr = lane & 15, lk = lane >> 4;

  const int r0 = tid >> 3, c8 = tid & 7;

  f32x4 acc[4][4];
#pragma unroll
  for (int m = 0; m < 4; ++m)
#pragma unroll
    for (int n = 0; n < 4; ++n) {
      acc[m][n][0] = 0.f; acc[m][n][1] = 0.f; acc[m][n][2] = 0.f; acc[m][n][3] = 0.f;
    }

  const int nk = K >> 6;
  for (int kt = 0; kt < nk; ++kt) {
    const ushort_t* Ak = Ab + kt * 64;
    const ushort_t* Bk = Bb + kt * 64;
    s16x8 ra[4], rb[4];
#pragma unroll
    for (int it = 0; it < 4; ++it) {
      int row = it * 32 + r0;
      ra[it] = *(const s16x8*)(Ak + (long long)row * lda + c8 * 8);
      rb[it] = *(const s16x8*)(Bk + (long long)row * ldb + c8 * 8);
    }
    __syncthreads();
#pragma unroll
    for (int it = 0; it < 4; ++it) {
      int row = it * 32 + r0;
      int sc = (c8 ^ (row & 7)) << 3;
      *(s16x8*)(&As[row * 64 + sc]) = ra[it];
      *(s16x8*)(&Bs[row * 64 + sc]) = rb[it];
    }
    __syncthreads();
#pragma unroll
    for (int kk = 0; kk < 2; ++kk) {
      s16x8 af[4], bv[4];
#pragma unroll
      for (int m = 0; m < 4; ++m) {
        int row = wr * 64 + m * 16 + lr;
        int cc = ((kk * 4 + lk) ^ (row & 7)) << 3;
        af[m] = *(const s16x8*)(&As[row * 64 + cc]);
      }
#pragma unroll
      for (int n = 0; n < 4; ++n) {
        int row = wc * 64 + n * 16 + lr;
        int cc = ((kk * 4 + lk) ^ (row & 7)) << 3;
        bv[n] = *(const s16x8*)(&Bs[row * 64 + cc]);
      }
#pragma unroll
      for (int m = 0; m < 4; ++m)
#pragma unroll
        for (int n = 0; n < 4; ++n)
          acc[m][n] = __builtin_amdgcn_mfma_f32_16x16x32_bf16(af[m], bv[n], acc[m][n], 0, 0, 0);
    }
  }

  const long long row0 = (long long)blockIdx.y * 128 + wr * 64 + lk * 4;
  const int col0 = blockIdx.x * 128 + wc * 64 + lr;
#pragma unroll
  for (int m = 0; m < 4; ++m)
#pragma unroll
    for (int n = 0; n < 4; ++n)
#pragma unroll
      for (int r = 0; r < 4; ++r) {
        long long row = row0 + m * 16 + r;
        int col = col0 + n * 16;
        float v = acc[m][n][r] * alpha;
        if (BIAS) v += bias[col] * bscale;
        if (RES) v += res[coff + row * ldc + col];
        if (ACT == ACT_RELU) v = fmaxf(v, 0.f);
        else if (ACT == ACT_GELU) v = 0.5f * v * (1.f + erff(v * 0.70710678118654752f));
        else if (ACT == ACT_SIGM) v = 1.f / (1.f + expf(-v));
        if (OBF) ((ushort_t*)C)[coff + row * ldc + col] = f2bfbits(v);
        else ((float*)C)[coff + row * ldc + col] = v;
      }
}

// =====================================================================
// Fused flash attention (one (b,h) pair per blockIdx.y, 128 Q-rows per block)
// o1 = softmax(Q K^T * scale) V  -> ob cols [h*256, h*256+128)
// Q,K from qkvt slices; V from pre-transposed Vt [pair][d=128][n=2048].
// 4 waves x 32 Q-rows; KV tiles of 64; online softmax in-register.
// =====================================================================
__global__ __launch_bounds__(256) void flash_attn(
    const ushort_t* __restrict__ qkvt,
    const ushort_t* __restrict__ Vt,
    ushort_t* __restrict__ ob,
    float scale)
{
  const int qb = blockIdx.x;     // 0..15
  const int pair = blockIdx.y;   // 0..31
  const int b = pair >> 2, hh = pair & 3;

  const int tid = threadIdx.x;
  const int lane = tid & 63, w = tid >> 6;
  const int lr = lane & 15, lk = lane >> 4;

  // padded LDS (row strides 272B / 144B -> bank-rotating, ~2-way max)
  __shared__ ushort_t Ks[64 * 136];       // [kv][d]   (d=128 + pad 8)
  __shared__ ushort_t Vs[128 * 72];       // [d][kv]   (kv=64 + pad 8)
  __shared__ ushort_t Ps[4 * 32 * 72];    // per-wave [qrow32][kv64 + pad 8]

  const ushort_t* Qbase = qkvt + ((long long)(b * 2048 + qb * 128 + w * 32)) * 2048 + hh * 128;
  const ushort_t* Kbase = qkvt + ((long long)b * 2048) * 2048 + 512 + hh * 128;
  const ushort_t* Vbase = Vt + (long long)pair * 128 * 2048;
  ushort_t* Pw = &Ps[w * 32 * 72];

  // Q fragments (A-layout: row=lane&15, k=(lane>>4)*8 within 32-slice)
  s16x8 qf[2][4];
#pragma unroll
  for (int m = 0; m < 2; ++m)
#pragma unroll
    for (int kf = 0; kf < 4; ++kf)
      qf[m][kf] = *(const s16x8*)(Qbase + (long long)(m * 16 + lr) * 2048 + kf * 32 + lk * 8);

  f32x4 accO[2][8];
#pragma unroll
  for (int m = 0; m < 2; ++m)
#pragma unroll
    for (int n = 0; n < 8; ++n) { accO[m][n][0] = 0.f; accO[m][n][1] = 0.f; accO[m][n][2] = 0.f; accO[m][n][3] = 0.f; }
  float mrun[2][4], lrun[2][4];
#pragma unroll
  for (int m = 0; m < 2; ++m)
#pragma unroll
    for (int r = 0; r < 4; ++r) { mrun[m][r] = -1e30f; lrun[m][r] = 0.f; }

  for (int t = 0; t < 32; ++t) {   // 2048 / 64 KV rows
    __syncthreads();
    // stage K tile [64][128] -> Ks
    {
      int r = tid >> 4, g = tid & 15;
#pragma unroll
      for (int ps = 0; ps < 4; ++ps) {
        int row = ps * 16 + r;
        *(s16x8*)(&Ks[row * 136 + g * 8]) =
            *(const s16x8*)(Kbase + (long long)(t * 64 + row) * 2048 + g * 8);
      }
    }
    // stage V tile [128 d][64 kv] -> Vs
    {
      int r = tid >> 3, g = tid & 7;
#pragma unroll
      for (int ps = 0; ps < 4; ++ps) {
        int row = ps * 32 + r;
        *(s16x8*)(&Vs[row * 72 + g * 8]) =
            *(const s16x8*)(Vbase + (long long)row * 2048 + t * 64 + g * 8);
      }
    }
    __syncthreads();

    // S = Q K^T  (accS[m][n]: rows m*16+lk*4+r, cols n*16+lr)
    f32x4 accS[2][4];
#pragma unroll
    for (int m = 0; m < 2; ++m)
#pragma unroll
      for (int n = 0; n < 4; ++n) { accS[m][n][0] = 0.f; accS[m][n][1] = 0.f; accS[m][n][2] = 0.f; accS[m][n][3] = 0.f; }
#pragma unroll
    for (int kf = 0; kf < 4; ++kf) {
      s16x8 kb[4];
#pragma unroll
      for (int n = 0; n < 4; ++n)
        kb[n] = *(const s16x8*)(&Ks[(n * 16 + lr) * 136 + kf * 32 + lk * 8]);
#pragma unroll
      for (int m = 0; m < 2; ++m)
#pragma unroll
        for (int n = 0; n < 4; ++n)
          accS[m][n] = __builtin_amdgcn_mfma_f32_16x16x32_bf16(qf[m][kf], kb[n], accS[m][n], 0, 0, 0);
    }
#pragma unroll
    for (int m = 0; m < 2; ++m)
#pragma unroll
      for (int n = 0; n < 4; ++n)
#pragma unroll
        for (int r = 0; r < 4; ++r) accS[m][n][r] *= scale;

    // online softmax
    float mnew[2][4], alpha[2][4], rsum[2][4];
#pragma unroll
    for (int m = 0; m < 2; ++m)
#pragma unroll
      for (int r = 0; r < 4; ++r) {
        float vmx = fmaxf(fmaxf(accS[m][0][r], accS[m][1][r]), fmaxf(accS[m][2][r], accS[m][3][r]));
        vmx = fmaxf(vmx, __shfl_xor(vmx, 1));
        vmx = fmaxf(vmx, __shfl_xor(vmx, 2));
        vmx = fmaxf(vmx, __shfl_xor(vmx, 4));
        vmx = fmaxf(vmx, __shfl_xor(vmx, 8));
        float mn = fmaxf(mrun[m][r], vmx);
        mnew[m][r] = mn;
        alpha[m][r] = expf(mrun[m][r] - mn);
        mrun[m][r] = mn;
        rsum[m][r] = 0.f;
      }
#pragma unroll
    for (int m = 0; m < 2; ++m)
#pragma unroll
      for (int n = 0; n < 4; ++n)
#pragma unroll
        for (int r = 0; r < 4; ++r) {
          float pv = expf(accS[m][n][r] - mnew[m][r]);
          rsum[m][r] += pv;
          Pw[(m * 16 + lk * 4 + r) * 72 + n * 16 + lr] = f2bfbits(pv);
        }
#pragma unroll
    for (int m = 0; m < 2; ++m)
#pragma unroll
      for (int r = 0; r < 4; ++r) {
        float s = rsum[m][r];
        s += __shfl_xor(s, 1);
        s += __shfl_xor(s, 2);
        s += __shfl_xor(s, 4);
        s += __shfl_xor(s, 8);
        lrun[m][r] = lrun[m][r] * alpha[m][r] + s;
      }
#pragma unroll
    for (int m = 0; m < 2; ++m)
#pragma unroll
      for (int n = 0; n < 8; ++n)
#pragma unroll
        for (int r = 0; r < 4; ++r) accO[m][n][r] *= alpha[m][r];

    // O += P V   (P A-frags from per-wave LDS; V B-frags from Vs)
#pragma unroll
    for (int ks = 0; ks < 2; ++ks) {
      s16x8 pa[2];
#pragma unroll
      for (int m = 0; m < 2; ++m)
        pa[m] = *(const s16x8*)(&Pw[(m * 16 + lr) * 72 + ks * 32 + lk * 8]);
#pragma unroll
      for (int n = 0; n < 8; ++n) {
        s16x8 vb = *(const s16x8*)(&Vs[(n * 16 + lr) * 72 + ks * 32 + lk * 8]);
#pragma unroll
        for (int m = 0; m < 2; ++m)
          accO[m][n] = __builtin_amdgcn_mfma_f32_16x16x32_bf16(pa[m], vb, accO[m][n], 0, 0, 0);
      }
    }
  }

  // epilogue: normalize and store to ob cols [hh*256, +128)
#pragma unroll
  for (int m = 0; m < 2; ++m)
#pragma unroll
    for (int r = 0; r < 4; ++r) {
      float linv = 1.f / lrun[m][r];
      long long row = (long long)b * 2048 + qb * 128 + w * 32 + m * 16 + lk * 4 + r;
#pragma unroll
      for (int n = 0; n < 8; ++n)
        ob[row * 1024 + hh * 256 + n * 16 + lr] = f2bfbits(accO[m][n][r] * linv);
    }
}

// =====================================================================
// LayerNorm: fp32 in (rows x 512) -> bf16 out
// =====================================================================
__global__ __launch_bounds__(256) void ln_kernel(const float* __restrict__ h,
                                                 const float* __restrict__ g,
                                                 const float* __restrict__ b,
                                                 ushort_t* __restrict__ out)
{
  const int D = 512;
  long long row = blockIdx.x;
  const float* x = h + row * D;
  int t = threadIdx.x;
  float v0 = x[t], v1 = x[t + 256];
  __shared__ float rs[256], rss[256];
  rs[t] = v0 + v1; rss[t] = v0 * v0 + v1 * v1;
  __syncthreads();
  for (int o = 128; o > 0; o >>= 1) {
    if (t < o) { rs[t] += rs[t + o]; rss[t] += rss[t + o]; }
    __syncthreads();
  }
  float mean = rs[0] * (1.f / D);
  float var = rss[0] * (1.f / D) - mean * mean;
  float inv = rsqrtf(var + 1e-5f);
  out[row * D + t] = f2bfbits((v0 - mean) * inv * g[t] + b[t]);
  out[row * D + t + 256] = f2bfbits((v1 - mean) * inv * g[t + 256] + b[t + 256]);
}

// =====================================================================
// x (8,2048,1024) fp32 -> zero-padded bf16 [8][2050][1024]
// =====================================================================
__global__ __launch_bounds__(256) void build_xpad(const float* __restrict__ x,
                                                  ushort_t* __restrict__ xp)
{
  long long idx = (long long)blockIdx.x * 256 + threadIdx.x;
  int c = (int)(idx % 1024);
  long long t = idx / 1024;
  int r = (int)(t % 2050);
  int b = (int)(t / 2050);
  float v = (r == 0 || r == 2049) ? 0.f : x[((long long)b * 2048 + (r - 1)) * 1024 + c];
  xp[idx] = f2bfbits(v);
}

// =====================================================================
// A2[i][j] = exp(-|i-j|/e) / sum_m exp(-|j-m|/e)  (closed-form column sums)
// =====================================================================
__global__ __launch_bounds__(256) void build_a2(ushort_t* __restrict__ A2)
{
  const int n = 2048;
  long long idx = (long long)blockIdx.x * 256 + threadIdx.x;
  int i = (int)(idx / n), j = (int)(idx % n);
  const float inv_e = 0.36787944117144233f;
  float w = expf(-fabsf((float)(i - j)) * inv_e);
  float r = expf(-inv_e);
  float geo = r / (1.f - r);
  float s = 1.f + geo * (1.f - expf(-inv_e * (float)j))
               + geo * (1.f - expf(-inv_e * (float)(n - 1 - j)));
  A2[idx] = f2bfbits(w / s);
}

// =====================================================================
// transpose + cast fp32 (R x C) -> bf16 (C x R), batched
// =====================================================================
__global__ __launch_bounds__(256) void tr_cast(const float* __restrict__ src0,
                                               ushort_t* __restrict__ dst0,
                                               int R, int C, long long ss, long long ds)
{
  const float* src = src0 + (long long)blockIdx.z * ss;
  ushort_t* dst = dst0 + (long long)blockIdx.z * ds;
  __shared__ float tile[32][33];
  int tx = threadIdx.x, ty = threadIdx.y;
#pragma unroll
  for (int i = 0; i < 4; ++i) {
    int r = blockIdx.y * 32 + ty + i * 8;
    int c = blockIdx.x * 32 + tx;
    tile[ty + i * 8][tx] = src[(long long)r * C + c];
  }
  __syncthreads();
#pragma unroll
  for (int i = 0; i < 4; ++i) {
    int rr = blockIdx.x * 32 + ty + i * 8;
    int cc = blockIdx.y * 32 + tx;
    dst[(long long)rr * R + cc] = f2bfbits(tile[tx][ty + i * 8]);
  }
}

// =====================================================================
// Per-(b,h) transpose of V/T slices of qkvt: out[p][d][n] (bf16)
// =====================================================================
__global__ __launch_bounds__(256) void tr_pair(const ushort_t* __restrict__ qkvt,
                                               ushort_t* __restrict__ out, int coloff)
{
  int p = blockIdx.z;
  int b = p >> 2, hh = p & 3;
  const ushort_t* src = qkvt + ((long long)b * 2048) * 2048 + coloff + hh * 128;
  ushort_t* dst = out + (long long)p * 128 * 2048;
  __shared__ ushort_t tile[32][33];
  int tx = threadIdx.x, ty = threadIdx.y;
  int n0 = blockIdx.x * 32, d0 = blockIdx.y * 32;
#pragma unroll
  for (int i = 0; i < 4; ++i)
    tile[ty + i * 8][tx] = src[(long long)(n0 + ty + i * 8) * 2048 + d0 + tx];
  __syncthreads();
#pragma unroll
  for (int i = 0; i < 4; ++i)
    dst[(long long)(d0 + ty + i * 8) * 2048 + n0 + tx] = tile[tx][ty + i * 8];
}

// =====================================================================
// memory banks: memc[128][512] = [amem(60); 0; nmem(60); 0], memTc = memc^T
// =====================================================================
__global__ __launch_bounds__(256) void build_mem(const float* __restrict__ amem,
                                                 const float* __restrict__ nmem,
                                                 ushort_t* __restrict__ memc,
                                                 ushort_t* __restrict__ memTc)
{
  int idx = blockIdx.x * 256 + threadIdx.x;
  int r = idx / 512, d = idx % 512;
  float v = 0.f;
  if (r < 60) v = amem[r * 512 + d];
  else if (r >= 64 && r < 124) v = nmem[(r - 64) * 512 + d];
  unsigned short u = f2bfbits(v);
  memc[idx] = u;
  memTc[d * 128 + r] = u;
}

// =====================================================================
// fp32 rows -> bf16 into strided dst (used for h -> z[:, :512])
// =====================================================================
__global__ __launch_bounds__(256) void cast_rows(const float* __restrict__ src,
                                                 ushort_t* __restrict__ dst,
                                                 int cols, int ldd)
{
  long long idx = (long long)blockIdx.x * 256 + threadIdx.x;
  long long r = idx / cols;
  int c = (int)(idx % cols);
  dst[r * ldd + c] = f2bfbits(src[idx]);
}

// =====================================================================
// final: out[row] = sigmoid( dot(relu_cls1[row], w2) + b2 )
// =====================================================================
__global__ __launch_bounds__(256) void cls2_kernel(const ushort_t* __restrict__ cls1,
                                                   const float* __restrict__ w2,
                                                   const float* __restrict__ b2,
                                                   float* __restrict__ out)
{
  int row = blockIdx.x * 4 + (threadIdx.x >> 6);
  int lane = threadIdx.x & 63;
  const ushort_t* rp = cls1 + (long long)row * 128;
  float v = bfbits2f(rp[lane]) * w2[lane] + bfbits2f(rp[lane + 64]) * w2[lane + 64];
#pragma unroll
  for (int m = 32; m > 0; m >>= 1) v += __shfl_xor(v, m, 64);
  if (lane == 0) out[row] = 1.f / (1.f + expf(-(v + b2[0])));
}

// =====================================================================
// host side
// =====================================================================
static inline void* carve(char*& p, size_t bytes) {
  void* r = (void*)p;
  p += (bytes + 255) & ~(size_t)255;
  return r;
}

template<int ACT, bool OBF, bool BIAS, bool RES>
static inline void gemm(hipStream_t st, const ushort_t* A, const ushort_t* B, void* C,
                        const float* bias, float bscale, const float* res,
                        int M, int N, int K, int lda, int ldb, int ldc, float alpha,
                        int Z, int nz2,
                        long long sA1, long long sA2, long long sB1, long long sB2,
                        long long sC1, long long sC2)
{
  dim3 grid(N / 128, M / 128, Z), blk(256, 1, 1);
  gemm_bf16<ACT, OBF, BIAS, RES><<<grid, blk, 0, st>>>(
      A, B, C, bias, bscale, res, K, lda, ldb, ldc, alpha, nz2,
      sA1, sA2, sB1, sB2, sC1, sC2);
}

extern "C" void kernel_launch(void* const* d_in, const int* in_sizes, int n_in,
                              void* d_out, int out_size, void* d_ws, size_t ws_size,
                              hipStream_t stream)
{
  (void)in_sizes; (void)n_in; (void)out_size; (void)ws_size;
  const float* x      = (const float*)d_in[0];
  const float* conv_w = (const float*)d_in[1];
  const float* conv_b = (const float*)d_in[2];
  const float* ln1_g  = (const float*)d_in[3];
  const float* ln1_b  = (const float*)d_in[4];
  const float* qkv_w  = (const float*)d_in[5];
  const float* out_w  = (const float*)d_in[6];
  const float* out_b  = (const float*)d_in[7];
  const float* ln2_g  = (const float*)d_in[8];
  const float* ln2_b  = (const float*)d_in[9];
  const float* ff_w1  = (const float*)d_in[10];
  const float* ff_b1  = (const float*)d_in[11];
  const float* ff_w2  = (const float*)d_in[12];
  const float* ff_b2  = (const float*)d_in[13];
  const float* amem   = (const float*)d_in[14];
  const float* nmem   = (const float*)d_in[15];
  const float* enc_w  = (const float*)d_in[16];
  const float* enc_b  = (const float*)d_in[17];
  const float* cls_w1 = (const float*)d_in[18];
  const float* cls_b1 = (const float*)d_in[19];
  const float* cls_w2 = (const float*)d_in[20];
  const float* cls_b2 = (const float*)d_in[21];
  float* outp = (float*)d_out;

  const long long M = 16384;
  const float att_scale = 0.08838834764831845f;   // 128^-0.5
  const float mem_scale = 0.04419417382415922f;   // 512^-0.5

  // ---- workspace layout with phase-based unions ----
  char* p = (char*)d_ws;
  float*    h    = (float*)   carve(p, (size_t)M * 512 * 4);           // persistent
  ushort_t* A2b  = (ushort_t*)carve(p, (size_t)2048 * 2048 * 2);       // persistent
  ushort_t* Wcat  = (ushort_t*)carve(p, (size_t)512 * 3072 * 2);
  ushort_t* qkvT  = (ushort_t*)carve(p, (size_t)2 * 2048 * 512 * 2);
  ushort_t* outT  = (ushort_t*)carve(p, (size_t)2 * 512 * 1024 * 2);
  ushort_t* f1T   = (ushort_t*)carve(p, (size_t)2 * 512 * 512 * 2);
  ushort_t* f2T   = (ushort_t*)carve(p, (size_t)2 * 512 * 512 * 2);
  ushort_t* encT  = (ushort_t*)carve(p, (size_t)512 * 512 * 2);
  ushort_t* c1T   = (ushort_t*)carve(p, (size_t)128 * 1024 * 2);
  ushort_t* memc  = (ushort_t*)carve(p, (size_t)128 * 512 * 2);
  ushort_t* memTc = (ushort_t*)carve(p, (size_t)512 * 128 * 2);
  // U1: xpad (conv) | Vt+Tt (attn) | ffb (ffn) | zb (final)
  char* U1 = (char*)carve(p, (size_t)8 * 2050 * 1024 * 2);
  ushort_t* xpad = (ushort_t*)U1;
  ushort_t* Vt   = (ushort_t*)U1;
  ushort_t* Tt   = (ushort_t*)(U1 + (size_t)32 * 128 * 2048 * 2);
  ushort_t* ffb  = (ushort_t*)U1;
  ushort_t* zb   = (ushort_t*)U1;
  // U2: qkvt (layers) | attb+m1b+cls1b (final)
  char* U2 = (char*)carve(p, (size_t)M * 2048 * 2);
  ushort_t* qkvt  = (ushort_t*)U2;
  ushort_t* attb  = (ushort_t*)U2;
  ushort_t* m1b   = (ushort_t*)(U2 + (size_t)M * 128 * 2);
  ushort_t* cls1b = (ushort_t*)(U2 + (size_t)M * 128 * 2 + (size_t)M * 512 * 2);
  ushort_t* ob = (ushort_t*)carve(p, (size_t)M * 1024 * 2);
  // U3: xn only (Sb eliminated by flash attention)
  ushort_t* xn = (ushort_t*)carve(p, (size_t)M * 512 * 2);

  dim3 tb(32, 8, 1);

  // ---- prep ----
  build_xpad<<<(8 * 2050 * 1024) / 256, 256, 0, stream>>>(x, xpad);
  build_a2<<<(2048 * 2048) / 256, 256, 0, stream>>>(A2b);
  tr_cast<<<dim3(512 / 32, 3072 / 32, 1), tb, 0, stream>>>(conv_w, Wcat, 3072, 512, 0, 0);
  tr_cast<<<dim3(2048 / 32, 512 / 32, 2), tb, 0, stream>>>(qkv_w, qkvT, 512, 2048,
      (long long)512 * 2048, (long long)2048 * 512);
  tr_cast<<<dim3(512 / 32, 1024 / 32, 2), tb, 0, stream>>>(out_w, outT, 1024, 512,
      (long long)1024 * 512, (long long)512 * 1024);
  tr_cast<<<dim3(512 / 32, 512 / 32, 2), tb, 0, stream>>>(ff_w1, f1T, 512, 512,
      (long long)512 * 512, (long long)512 * 512);
  tr_cast<<<dim3(512 / 32, 512 / 32, 2), tb, 0, stream>>>(ff_w2, f2T, 512, 512,
      (long long)512 * 512, (long long)512 * 512);
  tr_cast<<<dim3(512 / 32, 512 / 32, 1), tb, 0, stream>>>(enc_w, encT, 512, 512, 0, 0);
  tr_cast<<<dim3(128 / 32, 1024 / 32, 1), tb, 0, stream>>>(cls_w1, c1T, 1024, 128, 0, 0);
  build_mem<<<256, 256, 0, stream>>>(amem, nmem, memc, memTc);

  // ---- conv1d as K=3072 GEMM ----
  gemm<ACT_RELU, false, true, false>(stream, xpad, Wcat, h, conv_b, 1.f, nullptr,
      2048, 512, 3072, 1024, 3072, 512, 1.f,
      8, 8, 0, (long long)2050 * 1024, 0, 0, 0, (long long)2048 * 512);

  // ---- transformer layers ----
  for (int l = 0; l < 2; ++l) {
    ln_kernel<<<16384, 256, 0, stream>>>(h, ln1_g + l * 512, ln1_b + l * 512, xn);
    gemm<ACT_NONE, true, false, false>(stream, xn, qkvT + (long long)l * 2048 * 512, qkvt,
        nullptr, 1.f, nullptr, 16384, 2048, 512, 512, 512, 2048, 1.f,
        1, 1, 0, 0, 0, 0, 0, 0);
    tr_pair<<<dim3(64, 4, 32), tb, 0, stream>>>(qkvt, Vt, 1024);
    tr_pair<<<dim3(64, 4, 32), tb, 0, stream>>>(qkvt, Tt, 1536);
    // o2 = A2 @ t  -> ob cols [h*256+128, h*256+256)
    gemm<ACT_NONE, true, false, false>(stream, A2b, Tt, ob + 128, nullptr, 1.f, nullptr,
        2048, 128, 2048, 2048, 2048, 1024, 1.f,
        32, 4, 0, 0, (long long)4 * 128 * 2048, (long long)128 * 2048,
        (long long)2048 * 1024, 256);
    // o1 via fused flash attention -> ob cols [h*256, h*256+128)
    flash_attn<<<dim3(16, 32), 256, 0, stream>>>(qkvt, Vt, ob, att_scale);
    // h = ob @ out_w[l] + out_b + h
    gemm<ACT_NONE, false, true, true>(stream, ob, outT + (long long)l * 512 * 1024, h,
        out_b + l * 512, 1.f, h, 16384, 512, 1024, 1024, 1024, 512, 1.f,
        1, 1, 0, 0, 0, 0, 0, 0);
    ln_kernel<<<16384, 256, 0, stream>>>(h, ln2_g + l * 512, ln2_b + l * 512, xn);
    gemm<ACT_GELU, true, true, false>(stream, xn, f1T + (long long)l * 512 * 512, ffb,
        ff_b1 + l * 512, 1.f, nullptr, 16384, 512, 512, 512, 512, 512, 1.f,
        1, 1, 0, 0, 0, 0, 0, 0);
    gemm<ACT_NONE, false, true, true>(stream, ffb, f2T + (long long)l * 512 * 512, h,
        ff_b2 + l * 512, 1.f, h, 16384, 512, 512, 512, 512, 512, 1.f,
        1, 1, 0, 0, 0, 0, 0, 0);
  }

  // ---- memory retrieval + classifier ----
  cast_rows<<<(16384 * 512) / 256, 256, 0, stream>>>(h, zb, 512, 1024);
  gemm<ACT_SIGM, true, false, false>(stream, zb, memc, attb, nullptr, 1.f, nullptr,
      16384, 128, 512, 1024, 512, 128, mem_scale, 1, 1, 0, 0, 0, 0, 0, 0);
  gemm<ACT_NONE, true, false, false>(stream, attb, memTc, m1b, nullptr, 1.f, nullptr,
      16384, 512, 128, 128, 128, 512, 1.f, 1, 1, 0, 0, 0, 0, 0, 0);
  gemm<ACT_NONE, true, true, false>(stream, m1b, encT, zb + 512, enc_b, 2.f, nullptr,
      16384, 512, 512, 512, 512, 1024, 1.f, 1, 1, 0, 0, 0, 0, 0, 0);
  gemm<ACT_RELU, true, true, false>(stream, zb, c1T, cls1b, cls_b1, 1.f, nullptr,
      16384, 128, 1024, 1024, 1024, 128, 1.f, 1, 1, 0, 0, 0, 0, 0, 0);
  cls2_kernel<<<4096, 256, 0, stream>>>(cls1b, cls_w2, cls_b2, outp);
}

// Round 6
// 995.850 us; speedup vs baseline: 1.8174x; 1.2680x over previous
//
#include <hip/hip_runtime.h>
#include <hip/hip_bf16.h>
#include <math.h>

typedef __attribute__((ext_vector_type(4))) float f32x4;
typedef __attribute__((ext_vector_type(8))) short s16x8;
typedef unsigned short ushort_t;

// ---------- bf16 bit helpers (RNE) ----------
__device__ __forceinline__ float bfbits2f(unsigned short u) {
  unsigned int x = ((unsigned int)u) << 16;
  return __builtin_bit_cast(float, x);
}
__device__ __forceinline__ unsigned short f2bfbits(float f) {
  unsigned int x = __builtin_bit_cast(unsigned int, f);
  unsigned int r = x + 0x7fffu + ((x >> 16) & 1u);
  return (unsigned short)(r >> 16);
}

// async global->LDS, 16B per lane, dest = lds base + lane*16 (wave-uniform base)
__device__ __forceinline__ void gload_lds16(const ushort_t* g, ushort_t* l) {
  __builtin_amdgcn_global_load_lds(
      (const __attribute__((address_space(1))) unsigned int*)g,
      (__attribute__((address_space(3))) unsigned int*)l, 16, 0, 0);
}

// ---------- activation enum ----------
#define ACT_NONE 0
#define ACT_RELU 1
#define ACT_GELU 2
#define ACT_SIGM 3

// =====================================================================
// Generic bf16 MFMA GEMM, NT: C[M,N] = act(alpha*A[M,K]*B[N,K]^T + bias + res)
// 128x128 tile, BK=64, 256 thr (4 waves 2x2). global_load_lds staging with
// pre-swizzled SOURCE (involution: src granule = slot ^ (row&7)), linear dest,
// XOR-swizzled reads -> 0 bank conflicts (verified round 4/5 pattern).
// =====================================================================
template<int ACT, bool OBF, bool BIAS, bool RES>
__global__ __launch_bounds__(256) void gemm_bf16(
    const ushort_t* __restrict__ A, const ushort_t* __restrict__ B,
    void* __restrict__ C, const float* __restrict__ bias, float bscale,
    const float* __restrict__ res,
    int K, int lda, int ldb, int ldc, float alpha, int nz2,
    long long sA1, long long sA2, long long sB1, long long sB2,
    long long sC1, long long sC2)
{
  const int z = blockIdx.z;
  const int z1 = z / nz2, z2 = z % nz2;
  const ushort_t* Ab = A + z1 * sA1 + z2 * sA2 + (long long)blockIdx.y * 128 * lda;
  const ushort_t* Bb = B + z1 * sB1 + z2 * sB2 + (long long)blockIdx.x * 128 * ldb;
  const long long coff = z1 * sC1 + z2 * sC2;

  __shared__ ushort_t As[128 * 64];
  __shared__ ushort_t Bs[128 * 64];

  const int tid = threadIdx.x;
  const int lane = tid & 63, wid = tid >> 6;
  const int wr = wid >> 1, wc = wid & 1;
  const int lr = lane & 15, lk = lane >> 4;

  f32x4 acc[4][4];
#pragma unroll
  for (int m = 0; m < 4; ++m)
#pragma unroll
    for (int n = 0; n < 4; ++n) {
      acc[m][n][0] = 0.f; acc[m][n][1] = 0.f; acc[m][n][2] = 0.f; acc[m][n][3] = 0.f;
    }

  const int nk = K >> 6;
  for (int kt = 0; kt < nk; ++kt) {
    const ushort_t* Ak = Ab + kt * 64;
    const ushort_t* Bk = Bb + kt * 64;
    __syncthreads();   // previous iteration's LDS reads complete
#pragma unroll
    for (int i = 0; i < 4; ++i) {
      int c = wid * 4 + i;                 // 0..15 chunk (8 rows x 8 slots)
      int row = c * 8 + (lane >> 3);       // 0..127
      int slot = (lane & 7) ^ (row & 7);   // pre-swizzled source granule
      gload_lds16(Ak + (long long)row * lda + slot * 8, As + c * 512);
      gload_lds16(Bk + (long long)row * ldb + slot * 8, Bs + c * 512);
    }
    __syncthreads();   // drains vmcnt (gload_lds) per barrier semantics
#pragma unroll
    for (int kk = 0; kk < 2; ++kk) {
      s16x8 af[4], bv[4];
#pragma unroll
      for (int m = 0; m < 4; ++m) {
        int row = wr * 64 + m * 16 + lr;
        int cc = ((kk * 4 + lk) ^ (row & 7)) << 3;
        af[m] = *(const s16x8*)(&As[row * 64 + cc]);
      }
#pragma unroll
      for (int n = 0; n < 4; ++n) {
        int row = wc * 64 + n * 16 + lr;
        int cc = ((kk * 4 + lk) ^ (row & 7)) << 3;
        bv[n] = *(const s16x8*)(&Bs[row * 64 + cc]);
      }
#pragma unroll
      for (int m = 0; m < 4; ++m)
#pragma unroll
        for (int n = 0; n < 4; ++n)
          acc[m][n] = __builtin_amdgcn_mfma_f32_16x16x32_bf16(af[m], bv[n], acc[m][n], 0, 0, 0);
    }
  }

  const long long row0 = (long long)blockIdx.y * 128 + wr * 64 + lk * 4;
  const int col0 = blockIdx.x * 128 + wc * 64 + lr;
#pragma unroll
  for (int m = 0; m < 4; ++m)
#pragma unroll
    for (int n = 0; n < 4; ++n)
#pragma unroll
      for (int r = 0; r < 4; ++r) {
        long long row = row0 + m * 16 + r;
        int col = col0 + n * 16;
        float v = acc[m][n][r] * alpha;
        if (BIAS) v += bias[col] * bscale;
        if (RES) v += res[coff + row * ldc + col];
        if (ACT == ACT_RELU) v = fmaxf(v, 0.f);
        else if (ACT == ACT_GELU) v = 0.5f * v * (1.f + erff(v * 0.70710678118654752f));
        else if (ACT == ACT_SIGM) v = 1.f / (1.f + expf(-v));
        if (OBF) ((ushort_t*)C)[coff + row * ldc + col] = f2bfbits(v);
        else ((float*)C)[coff + row * ldc + col] = v;
      }
}

// =====================================================================
// Fused flash attention v2: 64 Q-rows/block (grid 32x32 = 1024 -> 4 blocks/CU),
// 4 waves x 16 Q-rows, KV tiles of 64. LDS 40KB, all XOR-slot-swizzled.
// K/V staged via pre-swizzled-source global_load_lds. Online softmax with
// defer-max (THR=8 scaled) and deferred l-reduction.
// =====================================================================
__global__ __launch_bounds__(256, 4) void flash_attn(
    const ushort_t* __restrict__ qkvt,
    const ushort_t* __restrict__ Vt,
    ushort_t* __restrict__ ob,
    float scale)
{
  const int qb = blockIdx.x;     // 0..31 (64 q-rows each)
  const int pair = blockIdx.y;   // 0..31
  const int b = pair >> 2, hh = pair & 3;

  const int tid = threadIdx.x;
  const int lane = tid & 63, w = tid >> 6;
  const int lr = lane & 15, lk = lane >> 4;

  __shared__ ushort_t Ks[64 * 128];      // [kv][d]  16KB, swizzled
  __shared__ ushort_t Vs[128 * 64];      // [d][kv]  16KB, swizzled
  __shared__ ushort_t Ps[4 * 16 * 64];   // per-wave [q16][kv64] 8KB, swizzled

  const ushort_t* Qbase = qkvt + ((long long)(b * 2048 + qb * 64 + w * 16)) * 2048 + hh * 128;
  const ushort_t* Kbase = qkvt + ((long long)b * 2048) * 2048 + 512 + hh * 128;
  const ushort_t* Vbase = Vt + (long long)pair * 128 * 2048;
  ushort_t* Pw = &Ps[w * 16 * 64];

  // Q fragments: lane (lr,lk) holds Q[w*16+lr][kf*32+lk*8 ..+7]
  s16x8 qf[4];
#pragma unroll
  for (int kf = 0; kf < 4; ++kf)
    qf[kf] = *(const s16x8*)(Qbase + (long long)lr * 2048 + kf * 32 + lk * 8);

  f32x4 accO[8];
#pragma unroll
  for (int n = 0; n < 8; ++n) { accO[n][0] = 0.f; accO[n][1] = 0.f; accO[n][2] = 0.f; accO[n][3] = 0.f; }
  float mrun[4], lpart[4];
#pragma unroll
  for (int r = 0; r < 4; ++r) { mrun[r] = -1e30f; lpart[r] = 0.f; }

  const float thr = 8.0f / scale;   // defer-max threshold in raw-score domain

  // staging lane constants
  const int krow_l = lane >> 4;                 // K: 4 rows/call, 16 slots
  const int kslot_l = lane & 15;
  const int vrow_l = lane >> 3;                 // V: 8 rows/call, 8 slots
  const int vslot_l = lane & 7;

  for (int t = 0; t < 32; ++t) {
    __syncthreads();
    // stage K[64][128] + V[128][64], pre-swizzled source granules
#pragma unroll
    for (int i = 0; i < 4; ++i) {
      int c = w * 4 + i;                        // 0..15
      int kr = c * 4 + krow_l;
      int ks_ = kslot_l ^ (kr & 7);
      gload_lds16(Kbase + (long long)(t * 64 + kr) * 2048 + ks_ * 8, Ks + c * 512);
      int vr = c * 8 + vrow_l;
      int vs_ = vslot_l ^ (vr & 7);
      gload_lds16(Vbase + (long long)vr * 2048 + t * 64 + vs_ * 8, Vs + c * 512);
    }
    __syncthreads();

    // S = Q K^T (raw, scale folded into exp later)
    f32x4 accS[4];
#pragma unroll
    for (int n = 0; n < 4; ++n) { accS[n][0] = 0.f; accS[n][1] = 0.f; accS[n][2] = 0.f; accS[n][3] = 0.f; }
#pragma unroll
    for (int kf = 0; kf < 4; ++kf) {
#pragma unroll
      for (int n = 0; n < 4; ++n) {
        s16x8 kb = *(const s16x8*)(&Ks[(n * 16 + lr) * 128 + (((kf * 4 + lk) ^ (lr & 7)) << 3)]);
        accS[n] = __builtin_amdgcn_mfma_f32_16x16x32_bf16(qf[kf], kb, accS[n], 0, 0, 0);
      }
    }

    // defer-max online softmax (rows lk*4+r, cols n*16+lr)
    float vmx[4];
#pragma unroll
    for (int r = 0; r < 4; ++r)
      vmx[r] = fmaxf(fmaxf(accS[0][r], accS[1][r]), fmaxf(accS[2][r], accS[3][r]));
    bool ok = true;
#pragma unroll
    for (int r = 0; r < 4; ++r) ok &= (vmx[r] <= mrun[r] + thr);
    if (!__all(ok)) {
#pragma unroll
      for (int r = 0; r < 4; ++r) {
        float mx = vmx[r];
        mx = fmaxf(mx, __shfl_xor(mx, 1));
        mx = fmaxf(mx, __shfl_xor(mx, 2));
        mx = fmaxf(mx, __shfl_xor(mx, 4));
        mx = fmaxf(mx, __shfl_xor(mx, 8));
        float mn = fmaxf(mrun[r], mx);
        float al = __expf(scale * (mrun[r] - mn));
        mrun[r] = mn;
        lpart[r] *= al;
#pragma unroll
        for (int n = 0; n < 8; ++n) accO[n][r] *= al;
      }
    }
    // P = exp(scale*(s - m)), per-lane partial sums, swizzled scalar store
#pragma unroll
    for (int n = 0; n < 4; ++n)
#pragma unroll
      for (int r = 0; r < 4; ++r) {
        float pv = __expf(scale * (accS[n][r] - mrun[r]));
        lpart[r] += pv;
        int prow = lk * 4 + r;
        int gidx = (n * 2 + (lr >> 3)) ^ (prow & 7);
        Pw[prow * 64 + gidx * 8 + (lr & 7)] = f2bfbits(pv);
      }
    // same-wave LDS W->R is in-order; no barrier needed (Pw is wave-private)

    // O += P V
#pragma unroll
    for (int ks = 0; ks < 2; ++ks) {
      s16x8 pa = *(const s16x8*)(&Pw[lr * 64 + (((ks * 4 + lk) ^ (lr & 7)) << 3)]);
#pragma unroll
      for (int n = 0; n < 8; ++n) {
        s16x8 vb = *(const s16x8*)(&Vs[(n * 16 + lr) * 64 + (((ks * 4 + lk) ^ (lr & 7)) << 3)]);
        accO[n] = __builtin_amdgcn_mfma_f32_16x16x32_bf16(pa, vb, accO[n], 0, 0, 0);
      }
    }
  }

  // epilogue: reduce l across the 16-lane col group, normalize, store
#pragma unroll
  for (int r = 0; r < 4; ++r) {
    float s = lpart[r];
    s += __shfl_xor(s, 1);
    s += __shfl_xor(s, 2);
    s += __shfl_xor(s, 4);
    s += __shfl_xor(s, 8);
    float linv = 1.f / s;
    long long row = (long long)b * 2048 + qb * 64 + w * 16 + lk * 4 + r;
#pragma unroll
    for (int n = 0; n < 8; ++n)
      ob[row * 1024 + hh * 256 + n * 16 + lr] = f2bfbits(accO[n][r] * linv);
  }
}

// =====================================================================
// LayerNorm: fp32 in (rows x 512) -> bf16 out
// =====================================================================
__global__ __launch_bounds__(256) void ln_kernel(const float* __restrict__ h,
                                                 const float* __restrict__ g,
                                                 const float* __restrict__ b,
                                                 ushort_t* __restrict__ out)
{
  const int D = 512;
  long long row = blockIdx.x;
  const float* x = h + row * D;
  int t = threadIdx.x;
  float v0 = x[t], v1 = x[t + 256];
  __shared__ float rs[256], rss[256];
  rs[t] = v0 + v1; rss[t] = v0 * v0 + v1 * v1;
  __syncthreads();
  for (int o = 128; o > 0; o >>= 1) {
    if (t < o) { rs[t] += rs[t + o]; rss[t] += rss[t + o]; }
    __syncthreads();
  }
  float mean = rs[0] * (1.f / D);
  float var = rss[0] * (1.f / D) - mean * mean;
  float inv = rsqrtf(var + 1e-5f);
  out[row * D + t] = f2bfbits((v0 - mean) * inv * g[t] + b[t]);
  out[row * D + t + 256] = f2bfbits((v1 - mean) * inv * g[t + 256] + b[t + 256]);
}

// =====================================================================
// x (8,2048,1024) fp32 -> zero-padded bf16 [8][2050][1024]
// =====================================================================
__global__ __launch_bounds__(256) void build_xpad(const float* __restrict__ x,
                                                  ushort_t* __restrict__ xp)
{
  long long idx = (long long)blockIdx.x * 256 + threadIdx.x;
  int c = (int)(idx % 1024);
  long long t = idx / 1024;
  int r = (int)(t % 2050);
  int b = (int)(t / 2050);
  float v = (r == 0 || r == 2049) ? 0.f : x[((long long)b * 2048 + (r - 1)) * 1024 + c];
  xp[idx] = f2bfbits(v);
}

// =====================================================================
// A2[i][j] = exp(-|i-j|/e) / sum_m exp(-|j-m|/e)  (closed-form column sums)
// =====================================================================
__global__ __launch_bounds__(256) void build_a2(ushort_t* __restrict__ A2)
{
  const int n = 2048;
  long long idx = (long long)blockIdx.x * 256 + threadIdx.x;
  int i = (int)(idx / n), j = (int)(idx % n);
  const float inv_e = 0.36787944117144233f;
  float w = expf(-fabsf((float)(i - j)) * inv_e);
  float r = expf(-inv_e);
  float geo = r / (1.f - r);
  float s = 1.f + geo * (1.f - expf(-inv_e * (float)j))
               + geo * (1.f - expf(-inv_e * (float)(n - 1 - j)));
  A2[idx] = f2bfbits(w / s);
}

// =====================================================================
// transpose + cast fp32 (R x C) -> bf16 (C x R), batched
// =====================================================================
__global__ __launch_bounds__(256) void tr_cast(const float* __restrict__ src0,
                                               ushort_t* __restrict__ dst0,
                                               int R, int C, long long ss, long long ds)
{
  const float* src = src0 + (long long)blockIdx.z * ss;
  ushort_t* dst = dst0 + (long long)blockIdx.z * ds;
  __shared__ float tile[32][33];
  int tx = threadIdx.x, ty = threadIdx.y;
#pragma unroll
  for (int i = 0; i < 4; ++i) {
    int r = blockIdx.y * 32 + ty + i * 8;
    int c = blockIdx.x * 32 + tx;
    tile[ty + i * 8][tx] = src[(long long)r * C + c];
  }
  __syncthreads();
#pragma unroll
  for (int i = 0; i < 4; ++i) {
    int rr = blockIdx.x * 32 + ty + i * 8;
    int cc = blockIdx.y * 32 + tx;
    dst[(long long)rr * R + cc] = f2bfbits(tile[tx][ty + i * 8]);
  }
}

// =====================================================================
// Per-(b,h) transpose of V/T slices of qkvt: out[p][d][n] (bf16)
// =====================================================================
__global__ __launch_bounds__(256) void tr_pair(const ushort_t* __restrict__ qkvt,
                                               ushort_t* __restrict__ out, int coloff)
{
  int p = blockIdx.z;
  int b = p >> 2, hh = p & 3;
  const ushort_t* src = qkvt + ((long long)b * 2048) * 2048 + coloff + hh * 128;
  ushort_t* dst = out + (long long)p * 128 * 2048;
  __shared__ ushort_t tile[32][33];
  int tx = threadIdx.x, ty = threadIdx.y;
  int n0 = blockIdx.x * 32, d0 = blockIdx.y * 32;
#pragma unroll
  for (int i = 0; i < 4; ++i)
    tile[ty + i * 8][tx] = src[(long long)(n0 + ty + i * 8) * 2048 + d0 + tx];
  __syncthreads();
#pragma unroll
  for (int i = 0; i < 4; ++i)
    dst[(long long)(d0 + ty + i * 8) * 2048 + n0 + tx] = tile[tx][ty + i * 8];
}

// =====================================================================
// memory banks: memc[128][512] = [amem(60); 0; nmem(60); 0], memTc = memc^T
// =====================================================================
__global__ __launch_bounds__(256) void build_mem(const float* __restrict__ amem,
                                                 const float* __restrict__ nmem,
                                                 ushort_t* __restrict__ memc,
                                                 ushort_t* __restrict__ memTc)
{
  int idx = blockIdx.x * 256 + threadIdx.x;
  int r = idx / 512, d = idx % 512;
  float v = 0.f;
  if (r < 60) v = amem[r * 512 + d];
  else if (r >= 64 && r < 124) v = nmem[(r - 64) * 512 + d];
  unsigned short u = f2bfbits(v);
  memc[idx] = u;
  memTc[d * 128 + r] = u;
}

// =====================================================================
// fp32 rows -> bf16 into strided dst (used for h -> z[:, :512])
// =====================================================================
__global__ __launch_bounds__(256) void cast_rows(const float* __restrict__ src,
                                                 ushort_t* __restrict__ dst,
                                                 int cols, int ldd)
{
  long long idx = (long long)blockIdx.x * 256 + threadIdx.x;
  long long r = idx / cols;
  int c = (int)(idx % cols);
  dst[r * ldd + c] = f2bfbits(src[idx]);
}

// =====================================================================
// final: out[row] = sigmoid( dot(relu_cls1[row], w2) + b2 )
// =====================================================================
__global__ __launch_bounds__(256) void cls2_kernel(const ushort_t* __restrict__ cls1,
                                                   const float* __restrict__ w2,
                                                   const float* __restrict__ b2,
                                                   float* __restrict__ out)
{
  int row = blockIdx.x * 4 + (threadIdx.x >> 6);
  int lane = threadIdx.x & 63;
  const ushort_t* rp = cls1 + (long long)row * 128;
  float v = bfbits2f(rp[lane]) * w2[lane] + bfbits2f(rp[lane + 64]) * w2[lane + 64];
#pragma unroll
  for (int m = 32; m > 0; m >>= 1) v += __shfl_xor(v, m, 64);
  if (lane == 0) out[row] = 1.f / (1.f + expf(-(v + b2[0])));
}

// =====================================================================
// host side
// =====================================================================
static inline void* carve(char*& p, size_t bytes) {
  void* r = (void*)p;
  p += (bytes + 255) & ~(size_t)255;
  return r;
}

template<int ACT, bool OBF, bool BIAS, bool RES>
static inline void gemm(hipStream_t st, const ushort_t* A, const ushort_t* B, void* C,
                        const float* bias, float bscale, const float* res,
                        int M, int N, int K, int lda, int ldb, int ldc, float alpha,
                        int Z, int nz2,
                        long long sA1, long long sA2, long long sB1, long long sB2,
                        long long sC1, long long sC2)
{
  dim3 grid(N / 128, M / 128, Z), blk(256, 1, 1);
  gemm_bf16<ACT, OBF, BIAS, RES><<<grid, blk, 0, st>>>(
      A, B, C, bias, bscale, res, K, lda, ldb, ldc, alpha, nz2,
      sA1, sA2, sB1, sB2, sC1, sC2);
}

extern "C" void kernel_launch(void* const* d_in, const int* in_sizes, int n_in,
                              void* d_out, int out_size, void* d_ws, size_t ws_size,
                              hipStream_t stream)
{
  (void)in_sizes; (void)n_in; (void)out_size; (void)ws_size;
  const float* x      = (const float*)d_in[0];
  const float* conv_w = (const float*)d_in[1];
  const float* conv_b = (const float*)d_in[2];
  const float* ln1_g  = (const float*)d_in[3];
  const float* ln1_b  = (const float*)d_in[4];
  const float* qkv_w  = (const float*)d_in[5];
  const float* out_w  = (const float*)d_in[6];
  const float* out_b  = (const float*)d_in[7];
  const float* ln2_g  = (const float*)d_in[8];
  const float* ln2_b  = (const float*)d_in[9];
  const float* ff_w1  = (const float*)d_in[10];
  const float* ff_b1  = (const float*)d_in[11];
  const float* ff_w2  = (const float*)d_in[12];
  const float* ff_b2  = (const float*)d_in[13];
  const float* amem   = (const float*)d_in[14];
  const float* nmem   = (const float*)d_in[15];
  const float* enc_w  = (const float*)d_in[16];
  const float* enc_b  = (const float*)d_in[17];
  const float* cls_w1 = (const float*)d_in[18];
  const float* cls_b1 = (const float*)d_in[19];
  const float* cls_w2 = (const float*)d_in[20];
  const float* cls_b2 = (const float*)d_in[21];
  float* outp = (float*)d_out;

  const long long M = 16384;
  const float att_scale = 0.08838834764831845f;   // 128^-0.5
  const float mem_scale = 0.04419417382415922f;   // 512^-0.5

  // ---- workspace layout with phase-based unions ----
  char* p = (char*)d_ws;
  float*    h    = (float*)   carve(p, (size_t)M * 512 * 4);           // persistent
  ushort_t* A2b  = (ushort_t*)carve(p, (size_t)2048 * 2048 * 2);       // persistent
  ushort_t* Wcat  = (ushort_t*)carve(p, (size_t)512 * 3072 * 2);
  ushort_t* qkvT  = (ushort_t*)carve(p, (size_t)2 * 2048 * 512 * 2);
  ushort_t* outT  = (ushort_t*)carve(p, (size_t)2 * 512 * 1024 * 2);
  ushort_t* f1T   = (ushort_t*)carve(p, (size_t)2 * 512 * 512 * 2);
  ushort_t* f2T   = (ushort_t*)carve(p, (size_t)2 * 512 * 512 * 2);
  ushort_t* encT  = (ushort_t*)carve(p, (size_t)512 * 512 * 2);
  ushort_t* c1T   = (ushort_t*)carve(p, (size_t)128 * 1024 * 2);
  ushort_t* memc  = (ushort_t*)carve(p, (size_t)128 * 512 * 2);
  ushort_t* memTc = (ushort_t*)carve(p, (size_t)512 * 128 * 2);
  // U1: xpad (conv) | Vt+Tt (attn) | ffb (ffn) | zb (final)
  char* U1 = (char*)carve(p, (size_t)8 * 2050 * 1024 * 2);
  ushort_t* xpad = (ushort_t*)U1;
  ushort_t* Vt   = (ushort_t*)U1;
  ushort_t* Tt   = (ushort_t*)(U1 + (size_t)32 * 128 * 2048 * 2);
  ushort_t* ffb  = (ushort_t*)U1;
  ushort_t* zb   = (ushort_t*)U1;
  // U2: qkvt (layers) | attb+m1b+cls1b (final)
  char* U2 = (char*)carve(p, (size_t)M * 2048 * 2);
  ushort_t* qkvt  = (ushort_t*)U2;
  ushort_t* attb  = (ushort_t*)U2;
  ushort_t* m1b   = (ushort_t*)(U2 + (size_t)M * 128 * 2);
  ushort_t* cls1b = (ushort_t*)(U2 + (size_t)M * 128 * 2 + (size_t)M * 512 * 2);
  ushort_t* ob = (ushort_t*)carve(p, (size_t)M * 1024 * 2);
  ushort_t* xn = (ushort_t*)carve(p, (size_t)M * 512 * 2);

  dim3 tb(32, 8, 1);

  // ---- prep ----
  build_xpad<<<(8 * 2050 * 1024) / 256, 256, 0, stream>>>(x, xpad);
  build_a2<<<(2048 * 2048) / 256, 256, 0, stream>>>(A2b);
  tr_cast<<<dim3(512 / 32, 3072 / 32, 1), tb, 0, stream>>>(conv_w, Wcat, 3072, 512, 0, 0);
  tr_cast<<<dim3(2048 / 32, 512 / 32, 2), tb, 0, stream>>>(qkv_w, qkvT, 512, 2048,
      (long long)512 * 2048, (long long)2048 * 512);
  tr_cast<<<dim3(512 / 32, 1024 / 32, 2), tb, 0, stream>>>(out_w, outT, 1024, 512,
      (long long)1024 * 512, (long long)512 * 1024);
  tr_cast<<<dim3(512 / 32, 512 / 32, 2), tb, 0, stream>>>(ff_w1, f1T, 512, 512,
      (long long)512 * 512, (long long)512 * 512);
  tr_cast<<<dim3(512 / 32, 512 / 32, 2), tb, 0, stream>>>(ff_w2, f2T, 512, 512,
      (long long)512 * 512, (long long)512 * 512);
  tr_cast<<<dim3(512 / 32, 512 / 32, 1), tb, 0, stream>>>(enc_w, encT, 512, 512, 0, 0);
  tr_cast<<<dim3(128 / 32, 1024 / 32, 1), tb, 0, stream>>>(cls_w1, c1T, 1024, 128, 0, 0);
  build_mem<<<256, 256, 0, stream>>>(amem, nmem, memc, memTc);

  // ---- conv1d as K=3072 GEMM ----
  gemm<ACT_RELU, false, true, false>(stream, xpad, Wcat, h, conv_b, 1.f, nullptr,
      2048, 512, 3072, 1024, 3072, 512, 1.f,
      8, 8, 0, (long long)2050 * 1024, 0, 0, 0, (long long)2048 * 512);

  // ---- transformer layers ----
  for (int l = 0; l < 2; ++l) {
    ln_kernel<<<16384, 256, 0, stream>>>(h, ln1_g + l * 512, ln1_b + l * 512, xn);
    gemm<ACT_NONE, true, false, false>(stream, xn, qkvT + (long long)l * 2048 * 512, qkvt,
        nullptr, 1.f, nullptr, 16384, 2048, 512, 512, 512, 2048, 1.f,
        1, 1, 0, 0, 0, 0, 0, 0);
    tr_pair<<<dim3(64, 4, 32), tb, 0, stream>>>(qkvt, Vt, 1024);
    tr_pair<<<dim3(64, 4, 32), tb, 0, stream>>>(qkvt, Tt, 1536);
    // o2 = A2 @ t  -> ob cols [h*256+128, h*256+256)
    gemm<ACT_NONE, true, false, false>(stream, A2b, Tt, ob + 128, nullptr, 1.f, nullptr,
        2048, 128, 2048, 2048, 2048, 1024, 1.f,
        32, 4, 0, 0, (long long)4 * 128 * 2048, (long long)128 * 2048,
        (long long)2048 * 1024, 256);
    // o1 via fused flash attention -> ob cols [h*256, h*256+128)
    flash_attn<<<dim3(32, 32), 256, 0, stream>>>(qkvt, Vt, ob, att_scale);
    // h = ob @ out_w[l] + out_b + h
    gemm<ACT_NONE, false, true, true>(stream, ob, outT + (long long)l * 512 * 1024, h,
        out_b + l * 512, 1.f, h, 16384, 512, 1024, 1024, 1024, 512, 1.f,
        1, 1, 0, 0, 0, 0, 0, 0);
    ln_kernel<<<16384, 256, 0, stream>>>(h, ln2_g + l * 512, ln2_b + l * 512, xn);
    gemm<ACT_GELU, true, true, false>(stream, xn, f1T + (long long)l * 512 * 512, ffb,
        ff_b1 + l * 512, 1.f, nullptr, 16384, 512, 512, 512, 512, 512, 1.f,
        1, 1, 0, 0, 0, 0, 0, 0);
    gemm<ACT_NONE, false, true, true>(stream, ffb, f2T + (long long)l * 512 * 512, h,
        ff_b2 + l * 512, 1.f, h, 16384, 512, 512, 512, 512, 512, 1.f,
        1, 1, 0, 0, 0, 0, 0, 0);
  }

  // ---- memory retrieval + classifier ----
  cast_rows<<<(16384 * 512) / 256, 256, 0, stream>>>(h, zb, 512, 1024);
  gemm<ACT_SIGM, true, false, false>(stream, zb, memc, attb, nullptr, 1.f, nullptr,
      16384, 128, 512, 1024, 512, 128, mem_scale, 1, 1, 0, 0, 0, 0, 0, 0);
  gemm<ACT_NONE, true, false, false>(stream, attb, memTc, m1b, nullptr, 1.f, nullptr,
      16384, 512, 128, 128, 128, 512, 1.f, 1, 1, 0, 0, 0, 0, 0, 0);
  gemm<ACT_NONE, true, true, false>(stream, m1b, encT, zb + 512, enc_b, 2.f, nullptr,
      16384, 512, 512, 512, 512, 1024, 1.f, 1, 1, 0, 0, 0, 0, 0, 0);
  gemm<ACT_RELU, true, true, false>(stream, zb, c1T, cls1b, cls_b1, 1.f, nullptr,
      16384, 128, 1024, 1024, 1024, 128, 1.f, 1, 1, 0, 0, 0, 0, 0, 0);
  cls2_kernel<<<4096, 256, 0, stream>>>(cls1b, cls_w2, cls_b2, outp);
}

// Round 7
// 937.351 us; speedup vs baseline: 1.9309x; 1.0624x over previous
//
#include <hip/hip_runtime.h>
#include <hip/hip_bf16.h>
#include <math.h>

typedef __attribute__((ext_vector_type(4))) float f32x4;
typedef __attribute__((ext_vector_type(8))) short s16x8;
typedef __attribute__((ext_vector_type(2))) unsigned int u32x2;
typedef unsigned short ushort_t;

// ---------- bf16 bit helpers (RNE) ----------
__device__ __forceinline__ float bfbits2f(unsigned short u) {
  unsigned int x = ((unsigned int)u) << 16;
  return __builtin_bit_cast(float, x);
}
__device__ __forceinline__ unsigned short f2bfbits(float f) {
  unsigned int x = __builtin_bit_cast(unsigned int, f);
  unsigned int r = x + 0x7fffu + ((x >> 16) & 1u);
  return (unsigned short)(r >> 16);
}

// async global->LDS, 16B per lane, dest = lds base + lane*16 (wave-uniform base)
__device__ __forceinline__ void gload_lds16(const ushort_t* g, ushort_t* l) {
  __builtin_amdgcn_global_load_lds(
      (const __attribute__((address_space(1))) unsigned int*)g,
      (__attribute__((address_space(3))) unsigned int*)l, 16, 0, 0);
}

// ---------- activation enum ----------
#define ACT_NONE 0
#define ACT_RELU 1
#define ACT_GELU 2
#define ACT_SIGM 3

// =====================================================================
// Generic bf16 MFMA GEMM, NT: C[M,N] = act(alpha*A[M,K]*B[N,K]^T + bias + res)
// 128x128 tile, BK=64, 256 thr (4 waves 2x2). global_load_lds staging with
// pre-swizzled SOURCE, linear dest, XOR-swizzled reads (0 conflicts).
// T1 XCD swizzle: flat-id remap so A-panel-sharing groups co-reside per XCD.
// =====================================================================
template<int ACT, bool OBF, bool BIAS, bool RES>
__global__ __launch_bounds__(256) void gemm_bf16(
    const ushort_t* __restrict__ A, const ushort_t* __restrict__ B,
    void* __restrict__ C, const float* __restrict__ bias, float bscale,
    const float* __restrict__ res,
    int K, int lda, int ldb, int ldc, float alpha, int nz2,
    long long sA1, long long sA2, long long sB1, long long sB2,
    long long sC1, long long sC2)
{
  // XCD-aware swizzle (grids are always %8==0 in this app -> bijective)
  const int flat = blockIdx.x + gridDim.x * (blockIdx.y + gridDim.y * blockIdx.z);
  const int cpx = (gridDim.x * gridDim.y * gridDim.z) >> 3;
  const int sw = (flat & 7) * cpx + (flat >> 3);
  const int bx = sw % gridDim.x;                 // col-block (fast within XCD chunk)
  const int rest = sw / gridDim.x;
  const int by = rest % gridDim.y;               // row-block
  const int bz = rest / gridDim.y;

  const int z1 = bz / nz2, z2 = bz % nz2;
  const ushort_t* Ab = A + z1 * sA1 + z2 * sA2 + (long long)by * 128 * lda;
  const ushort_t* Bb = B + z1 * sB1 + z2 * sB2 + (long long)bx * 128 * ldb;
  const long long coff = z1 * sC1 + z2 * sC2;

  __shared__ ushort_t As[128 * 64];
  __shared__ ushort_t Bs[128 * 64];

  const int tid = threadIdx.x;
  const int lane = tid & 63, wid = tid >> 6;
  const int wr = wid >> 1, wc = wid & 1;
  const int lr = lane & 15, lk = lane >> 4;

  f32x4 acc[4][4];
#pragma unroll
  for (int m = 0; m < 4; ++m)
#pragma unroll
    for (int n = 0; n < 4; ++n) {
      acc[m][n][0] = 0.f; acc[m][n][1] = 0.f; acc[m][n][2] = 0.f; acc[m][n][3] = 0.f;
    }

  const int nk = K >> 6;
  for (int kt = 0; kt < nk; ++kt) {
    const ushort_t* Ak = Ab + kt * 64;
    const ushort_t* Bk = Bb + kt * 64;
    __syncthreads();
#pragma unroll
    for (int i = 0; i < 4; ++i) {
      int c = wid * 4 + i;
      int row = c * 8 + (lane >> 3);
      int slot = (lane & 7) ^ (row & 7);
      gload_lds16(Ak + (long long)row * lda + slot * 8, As + c * 512);
      gload_lds16(Bk + (long long)row * ldb + slot * 8, Bs + c * 512);
    }
    __syncthreads();
#pragma unroll
    for (int kk = 0; kk < 2; ++kk) {
      s16x8 af[4], bv[4];
#pragma unroll
      for (int m = 0; m < 4; ++m) {
        int row = wr * 64 + m * 16 + lr;
        int cc = ((kk * 4 + lk) ^ (row & 7)) << 3;
        af[m] = *(const s16x8*)(&As[row * 64 + cc]);
      }
#pragma unroll
      for (int n = 0; n < 4; ++n) {
        int row = wc * 64 + n * 16 + lr;
        int cc = ((kk * 4 + lk) ^ (row & 7)) << 3;
        bv[n] = *(const s16x8*)(&Bs[row * 64 + cc]);
      }
#pragma unroll
      for (int m = 0; m < 4; ++m)
#pragma unroll
        for (int n = 0; n < 4; ++n)
          acc[m][n] = __builtin_amdgcn_mfma_f32_16x16x32_bf16(af[m], bv[n], acc[m][n], 0, 0, 0);
    }
  }

  const long long row0 = (long long)by * 128 + wr * 64 + lk * 4;
  const int col0 = bx * 128 + wc * 64 + lr;
#pragma unroll
  for (int m = 0; m < 4; ++m)
#pragma unroll
    for (int n = 0; n < 4; ++n)
#pragma unroll
      for (int r = 0; r < 4; ++r) {
        long long row = row0 + m * 16 + r;
        int col = col0 + n * 16;
        float v = acc[m][n][r] * alpha;
        if (BIAS) v += bias[col] * bscale;
        if (RES) v += res[coff + row * ldc + col];
        if (ACT == ACT_RELU) v = fmaxf(v, 0.f);
        else if (ACT == ACT_GELU) v = 0.5f * v * (1.f + erff(v * 0.70710678118654752f));
        else if (ACT == ACT_SIGM) v = 1.f / (1.f + expf(-v));
        if (OBF) ((ushort_t*)C)[coff + row * ldc + col] = f2bfbits(v);
        else ((float*)C)[coff + row * ldc + col] = v;
      }
}

// =====================================================================
// Fused flash attention v3: swapped QK^T (A=K, B=Q) -> lane holds
// S[q=lr][kv=n*16+lk*4+r]: per-lane softmax (no shfl common path), P packed
// as b64 writes (4/tile, conflict-free pattern). Defer-max kept.
// 64 Q-rows/block, 4 waves x 16 Q-rows, KV tiles 64, LDS 40KB.
// =====================================================================
__global__ __launch_bounds__(256, 4) void flash_attn(
    const ushort_t* __restrict__ qkvt,
    const ushort_t* __restrict__ Vt,
    ushort_t* __restrict__ ob,
    float scale)
{
  // XCD swizzle (1024 blocks -> 128/XCD = 4 consecutive pairs per XCD)
  const int flat = blockIdx.x + gridDim.x * blockIdx.y;
  const int cpx = (gridDim.x * gridDim.y) >> 3;
  const int sw = (flat & 7) * cpx + (flat >> 3);
  const int qb = sw % gridDim.x;       // 0..31
  const int pair = sw / gridDim.x;     // 0..31
  const int b = pair >> 2, hh = pair & 3;

  const int tid = threadIdx.x;
  const int lane = tid & 63, w = tid >> 6;
  const int lr = lane & 15, lk = lane >> 4;

  __shared__ ushort_t Ks[64 * 128];      // [kv][d]  16KB, swizzled
  __shared__ ushort_t Vs[128 * 64];      // [d][kv]  16KB, swizzled
  __shared__ ushort_t Ps[4 * 16 * 64];   // per-wave [q16][kv64] 8KB, swizzled

  const ushort_t* Qbase = qkvt + ((long long)(b * 2048 + qb * 64 + w * 16)) * 2048 + hh * 128;
  const ushort_t* Kbase = qkvt + ((long long)b * 2048) * 2048 + 512 + hh * 128;
  const ushort_t* Vbase = Vt + (long long)pair * 128 * 2048;
  ushort_t* Pw = &Ps[w * 16 * 64];

  // Q fragments (B-operand; row index = lane&15 = q-row lr)
  s16x8 qf[4];
#pragma unroll
  for (int kf = 0; kf < 4; ++kf)
    qf[kf] = *(const s16x8*)(Qbase + (long long)lr * 2048 + kf * 32 + lk * 8);

  f32x4 accO[8];
#pragma unroll
  for (int n = 0; n < 8; ++n) { accO[n][0] = 0.f; accO[n][1] = 0.f; accO[n][2] = 0.f; accO[n][3] = 0.f; }
  float mrun = -1e30f, lpart = 0.f;     // per-lane state for q = lr
  const float thr = 8.0f / scale;

  const int krow_l = lane >> 4;
  const int kslot_l = lane & 15;
  const int vrow_l = lane >> 3;
  const int vslot_l = lane & 7;

  for (int t = 0; t < 32; ++t) {
    __syncthreads();
#pragma unroll
    for (int i = 0; i < 4; ++i) {
      int c = w * 4 + i;
      int kr = c * 4 + krow_l;
      int ks_ = kslot_l ^ (kr & 7);
      gload_lds16(Kbase + (long long)(t * 64 + kr) * 2048 + ks_ * 8, Ks + c * 512);
      int vr = c * 8 + vrow_l;
      int vs_ = vslot_l ^ (vr & 7);
      gload_lds16(Vbase + (long long)vr * 2048 + t * 64 + vs_ * 8, Vs + c * 512);
    }
    __syncthreads();

    // S^T = K Q^T : accS[n][r] = S[q=lr][kv = t*64 + n*16 + lk*4 + r]
    f32x4 accS[4];
#pragma unroll
    for (int n = 0; n < 4; ++n) { accS[n][0] = 0.f; accS[n][1] = 0.f; accS[n][2] = 0.f; accS[n][3] = 0.f; }
#pragma unroll
    for (int kf = 0; kf < 4; ++kf) {
#pragma unroll
      for (int n = 0; n < 4; ++n) {
        s16x8 kb = *(const s16x8*)(&Ks[(n * 16 + lr) * 128 + (((kf * 4 + lk) ^ (lr & 7)) << 3)]);
        accS[n] = __builtin_amdgcn_mfma_f32_16x16x32_bf16(kb, qf[kf], accS[n], 0, 0, 0);
      }
    }

    // per-lane max over this lane's 16 kv values
    float vmx = accS[0][0];
#pragma unroll
    for (int n = 0; n < 4; ++n)
#pragma unroll
      for (int r = 0; r < 4; ++r) vmx = fmaxf(vmx, accS[n][r]);

    if (!__all(vmx <= mrun + thr)) {
      // row max across the 4 lanes sharing q=lr
      float mx = vmx;
      mx = fmaxf(mx, __shfl_xor(mx, 16, 64));
      mx = fmaxf(mx, __shfl_xor(mx, 32, 64));
      float mn = fmaxf(mrun, mx);
      float al = __expf(scale * (mrun - mn));
      mrun = mn;
      lpart *= al;
      float alO[4];
#pragma unroll
      for (int r = 0; r < 4; ++r)
        alO[r] = __shfl(al, (lane & 48) | (lk * 4 + r), 64);
#pragma unroll
      for (int n = 0; n < 8; ++n)
#pragma unroll
        for (int r = 0; r < 4; ++r) accO[n][r] *= alO[r];
    }

    // P = exp(scale*s - scale*m): 4 consecutive kv per lane -> packed b64 write
    const float sm = scale * mrun;
#pragma unroll
    for (int n = 0; n < 4; ++n) {
      float p0 = __expf(scale * accS[n][0] - sm);
      float p1 = __expf(scale * accS[n][1] - sm);
      float p2 = __expf(scale * accS[n][2] - sm);
      float p3 = __expf(scale * accS[n][3] - sm);
      lpart += p0 + p1 + p2 + p3;
      u32x2 pk;
      pk[0] = (unsigned)f2bfbits(p0) | ((unsigned)f2bfbits(p1) << 16);
      pk[1] = (unsigned)f2bfbits(p2) | ((unsigned)f2bfbits(p3) << 16);
      int g = (n * 2 + (lk >> 1)) ^ (lr & 7);
      *(u32x2*)(&Pw[lr * 64 + g * 8 + (lk & 1) * 4]) = pk;
    }
    // Pw is wave-private; same-wave LDS W->R ordered by compiler waitcnt

    // O += P V
#pragma unroll
    for (int ks = 0; ks < 2; ++ks) {
      s16x8 pa = *(const s16x8*)(&Pw[lr * 64 + (((ks * 4 + lk) ^ (lr & 7)) << 3)]);
#pragma unroll
      for (int n = 0; n < 8; ++n) {
        s16x8 vb = *(const s16x8*)(&Vs[(n * 16 + lr) * 64 + (((ks * 4 + lk) ^ (lr & 7)) << 3)]);
        accO[n] = __builtin_amdgcn_mfma_f32_16x16x32_bf16(pa, vb, accO[n], 0, 0, 0);
      }
    }
  }

  // epilogue: reduce l across 4 lanes of q=lr, broadcast to O-lanes, store
  float Lrow = lpart;
  Lrow += __shfl_xor(Lrow, 16, 64);
  Lrow += __shfl_xor(Lrow, 32, 64);
  float linv_q = 1.f / Lrow;
  float linvO[4];
#pragma unroll
  for (int r = 0; r < 4; ++r)
    linvO[r] = __shfl(linv_q, (lane & 48) | (lk * 4 + r), 64);
#pragma unroll
  for (int r = 0; r < 4; ++r) {
    long long row = (long long)b * 2048 + qb * 64 + w * 16 + lk * 4 + r;
#pragma unroll
    for (int n = 0; n < 8; ++n)
      ob[row * 1024 + hh * 256 + n * 16 + lr] = f2bfbits(accO[n][r] * linvO[r]);
  }
}

// =====================================================================
// LayerNorm: fp32 in (rows x 512) -> bf16 out
// =====================================================================
__global__ __launch_bounds__(256) void ln_kernel(const float* __restrict__ h,
                                                 const float* __restrict__ g,
                                                 const float* __restrict__ b,
                                                 ushort_t* __restrict__ out)
{
  const int D = 512;
  long long row = blockIdx.x;
  const float* x = h + row * D;
  int t = threadIdx.x;
  float v0 = x[t], v1 = x[t + 256];
  __shared__ float rs[256], rss[256];
  rs[t] = v0 + v1; rss[t] = v0 * v0 + v1 * v1;
  __syncthreads();
  for (int o = 128; o > 0; o >>= 1) {
    if (t < o) { rs[t] += rs[t + o]; rss[t] += rss[t + o]; }
    __syncthreads();
  }
  float mean = rs[0] * (1.f / D);
  float var = rss[0] * (1.f / D) - mean * mean;
  float inv = rsqrtf(var + 1e-5f);
  out[row * D + t] = f2bfbits((v0 - mean) * inv * g[t] + b[t]);
  out[row * D + t + 256] = f2bfbits((v1 - mean) * inv * g[t + 256] + b[t + 256]);
}

// =====================================================================
// x (8,2048,1024) fp32 -> zero-padded bf16 [8][2050][1024]
// =====================================================================
__global__ __launch_bounds__(256) void build_xpad(const float* __restrict__ x,
                                                  ushort_t* __restrict__ xp)
{
  long long idx = (long long)blockIdx.x * 256 + threadIdx.x;
  int c = (int)(idx % 1024);
  long long t = idx / 1024;
  int r = (int)(t % 2050);
  int b = (int)(t / 2050);
  float v = (r == 0 || r == 2049) ? 0.f : x[((long long)b * 2048 + (r - 1)) * 1024 + c];
  xp[idx] = f2bfbits(v);
}

// =====================================================================
// A2[i][j] = exp(-|i-j|/e) / sum_m exp(-|j-m|/e)
// =====================================================================
__global__ __launch_bounds__(256) void build_a2(ushort_t* __restrict__ A2)
{
  const int n = 2048;
  long long idx = (long long)blockIdx.x * 256 + threadIdx.x;
  int i = (int)(idx / n), j = (int)(idx % n);
  const float inv_e = 0.36787944117144233f;
  float w = expf(-fabsf((float)(i - j)) * inv_e);
  float r = expf(-inv_e);
  float geo = r / (1.f - r);
  float s = 1.f + geo * (1.f - expf(-inv_e * (float)j))
               + geo * (1.f - expf(-inv_e * (float)(n - 1 - j)));
  A2[idx] = f2bfbits(w / s);
}

// =====================================================================
// transpose + cast fp32 (R x C) -> bf16 (C x R), batched
// =====================================================================
__global__ __launch_bounds__(256) void tr_cast(const float* __restrict__ src0,
                                               ushort_t* __restrict__ dst0,
                                               int R, int C, long long ss, long long ds)
{
  const float* src = src0 + (long long)blockIdx.z * ss;
  ushort_t* dst = dst0 + (long long)blockIdx.z * ds;
  __shared__ float tile[32][33];
  int tx = threadIdx.x, ty = threadIdx.y;
#pragma unroll
  for (int i = 0; i < 4; ++i) {
    int r = blockIdx.y * 32 + ty + i * 8;
    int c = blockIdx.x * 32 + tx;
    tile[ty + i * 8][tx] = src[(long long)r * C + c];
  }
  __syncthreads();
#pragma unroll
  for (int i = 0; i < 4; ++i) {
    int rr = blockIdx.x * 32 + ty + i * 8;
    int cc = blockIdx.y * 32 + tx;
    dst[(long long)rr * R + cc] = f2bfbits(tile[tx][ty + i * 8]);
  }
}

// =====================================================================
// Per-(b,h) transpose of V/T slices of qkvt: out[p][d][n] (bf16)
// =====================================================================
__global__ __launch_bounds__(256) void tr_pair(const ushort_t* __restrict__ qkvt,
                                               ushort_t* __restrict__ out, int coloff)
{
  int p = blockIdx.z;
  int b = p >> 2, hh = p & 3;
  const ushort_t* src = qkvt + ((long long)b * 2048) * 2048 + coloff + hh * 128;
  ushort_t* dst = out + (long long)p * 128 * 2048;
  __shared__ ushort_t tile[32][33];
  int tx = threadIdx.x, ty = threadIdx.y;
  int n0 = blockIdx.x * 32, d0 = blockIdx.y * 32;
#pragma unroll
  for (int i = 0; i < 4; ++i)
    tile[ty + i * 8][tx] = src[(long long)(n0 + ty + i * 8) * 2048 + d0 + tx];
  __syncthreads();
#pragma unroll
  for (int i = 0; i < 4; ++i)
    dst[(long long)(d0 + ty + i * 8) * 2048 + n0 + tx] = tile[tx][ty + i * 8];
}

// =====================================================================
// memory banks: memc[128][512] = [amem(60); 0; nmem(60); 0], memTc = memc^T
// =====================================================================
__global__ __launch_bounds__(256) void build_mem(const float* __restrict__ amem,
                                                 const float* __restrict__ nmem,
                                                 ushort_t* __restrict__ memc,
                                                 ushort_t* __restrict__ memTc)
{
  int idx = blockIdx.x * 256 + threadIdx.x;
  int r = idx / 512, d = idx % 512;
  float v = 0.f;
  if (r < 60) v = amem[r * 512 + d];
  else if (r >= 64 && r < 124) v = nmem[(r - 64) * 512 + d];
  unsigned short u = f2bfbits(v);
  memc[idx] = u;
  memTc[d * 128 + r] = u;
}

// =====================================================================
// fp32 rows -> bf16 into strided dst
// =====================================================================
__global__ __launch_bounds__(256) void cast_rows(const float* __restrict__ src,
                                                 ushort_t* __restrict__ dst,
                                                 int cols, int ldd)
{
  long long idx = (long long)blockIdx.x * 256 + threadIdx.x;
  long long r = idx / cols;
  int c = (int)(idx % cols);
  dst[r * ldd + c] = f2bfbits(src[idx]);
}

// =====================================================================
// final: out[row] = sigmoid( dot(relu_cls1[row], w2) + b2 )
// =====================================================================
__global__ __launch_bounds__(256) void cls2_kernel(const ushort_t* __restrict__ cls1,
                                                   const float* __restrict__ w2,
                                                   const float* __restrict__ b2,
                                                   float* __restrict__ out)
{
  int row = blockIdx.x * 4 + (threadIdx.x >> 6);
  int lane = threadIdx.x & 63;
  const ushort_t* rp = cls1 + (long long)row * 128;
  float v = bfbits2f(rp[lane]) * w2[lane] + bfbits2f(rp[lane + 64]) * w2[lane + 64];
#pragma unroll
  for (int m = 32; m > 0; m >>= 1) v += __shfl_xor(v, m, 64);
  if (lane == 0) out[row] = 1.f / (1.f + expf(-(v + b2[0])));
}

// =====================================================================
// host side
// =====================================================================
static inline void* carve(char*& p, size_t bytes) {
  void* r = (void*)p;
  p += (bytes + 255) & ~(size_t)255;
  return r;
}

template<int ACT, bool OBF, bool BIAS, bool RES>
static inline void gemm(hipStream_t st, const ushort_t* A, const ushort_t* B, void* C,
                        const float* bias, float bscale, const float* res,
                        int M, int N, int K, int lda, int ldb, int ldc, float alpha,
                        int Z, int nz2,
                        long long sA1, long long sA2, long long sB1, long long sB2,
                        long long sC1, long long sC2)
{
  dim3 grid(N / 128, M / 128, Z), blk(256, 1, 1);
  gemm_bf16<ACT, OBF, BIAS, RES><<<grid, blk, 0, st>>>(
      A, B, C, bias, bscale, res, K, lda, ldb, ldc, alpha, nz2,
      sA1, sA2, sB1, sB2, sC1, sC2);
}

extern "C" void kernel_launch(void* const* d_in, const int* in_sizes, int n_in,
                              void* d_out, int out_size, void* d_ws, size_t ws_size,
                              hipStream_t stream)
{
  (void)in_sizes; (void)n_in; (void)out_size; (void)ws_size;
  const float* x      = (const float*)d_in[0];
  const float* conv_w = (const float*)d_in[1];
  const float* conv_b = (const float*)d_in[2];
  const float* ln1_g  = (const float*)d_in[3];
  const float* ln1_b  = (const float*)d_in[4];
  const float* qkv_w  = (const float*)d_in[5];
  const float* out_w  = (const float*)d_in[6];
  const float* out_b  = (const float*)d_in[7];
  const float* ln2_g  = (const float*)d_in[8];
  const float* ln2_b  = (const float*)d_in[9];
  const float* ff_w1  = (const float*)d_in[10];
  const float* ff_b1  = (const float*)d_in[11];
  const float* ff_w2  = (const float*)d_in[12];
  const float* ff_b2  = (const float*)d_in[13];
  const float* amem   = (const float*)d_in[14];
  const float* nmem   = (const float*)d_in[15];
  const float* enc_w  = (const float*)d_in[16];
  const float* enc_b  = (const float*)d_in[17];
  const float* cls_w1 = (const float*)d_in[18];
  const float* cls_b1 = (const float*)d_in[19];
  const float* cls_w2 = (const float*)d_in[20];
  const float* cls_b2 = (const float*)d_in[21];
  float* outp = (float*)d_out;

  const long long M = 16384;
  const float att_scale = 0.08838834764831845f;   // 128^-0.5
  const float mem_scale = 0.04419417382415922f;   // 512^-0.5

  // ---- workspace layout with phase-based unions ----
  char* p = (char*)d_ws;
  float*    h    = (float*)   carve(p, (size_t)M * 512 * 4);
  ushort_t* A2b  = (ushort_t*)carve(p, (size_t)2048 * 2048 * 2);
  ushort_t* Wcat  = (ushort_t*)carve(p, (size_t)512 * 3072 * 2);
  ushort_t* qkvT  = (ushort_t*)carve(p, (size_t)2 * 2048 * 512 * 2);
  ushort_t* outT  = (ushort_t*)carve(p, (size_t)2 * 512 * 1024 * 2);
  ushort_t* f1T   = (ushort_t*)carve(p, (size_t)2 * 512 * 512 * 2);
  ushort_t* f2T   = (ushort_t*)carve(p, (size_t)2 * 512 * 512 * 2);
  ushort_t* encT  = (ushort_t*)carve(p, (size_t)512 * 512 * 2);
  ushort_t* c1T   = (ushort_t*)carve(p, (size_t)128 * 1024 * 2);
  ushort_t* memc  = (ushort_t*)carve(p, (size_t)128 * 512 * 2);
  ushort_t* memTc = (ushort_t*)carve(p, (size_t)512 * 128 * 2);
  char* U1 = (char*)carve(p, (size_t)8 * 2050 * 1024 * 2);
  ushort_t* xpad = (ushort_t*)U1;
  ushort_t* Vt   = (ushort_t*)U1;
  ushort_t* Tt   = (ushort_t*)(U1 + (size_t)32 * 128 * 2048 * 2);
  ushort_t* ffb  = (ushort_t*)U1;
  ushort_t* zb   = (ushort_t*)U1;
  char* U2 = (char*)carve(p, (size_t)M * 2048 * 2);
  ushort_t* qkvt  = (ushort_t*)U2;
  ushort_t* attb  = (ushort_t*)U2;
  ushort_t* m1b   = (ushort_t*)(U2 + (size_t)M * 128 * 2);
  ushort_t* cls1b = (ushort_t*)(U2 + (size_t)M * 128 * 2 + (size_t)M * 512 * 2);
  ushort_t* ob = (ushort_t*)carve(p, (size_t)M * 1024 * 2);
  ushort_t* xn = (ushort_t*)carve(p, (size_t)M * 512 * 2);

  dim3 tb(32, 8, 1);

  // ---- prep ----
  build_xpad<<<(8 * 2050 * 1024) / 256, 256, 0, stream>>>(x, xpad);
  build_a2<<<(2048 * 2048) / 256, 256, 0, stream>>>(A2b);
  tr_cast<<<dim3(512 / 32, 3072 / 32, 1), tb, 0, stream>>>(conv_w, Wcat, 3072, 512, 0, 0);
  tr_cast<<<dim3(2048 / 32, 512 / 32, 2), tb, 0, stream>>>(qkv_w, qkvT, 512, 2048,
      (long long)512 * 2048, (long long)2048 * 512);
  tr_cast<<<dim3(512 / 32, 1024 / 32, 2), tb, 0, stream>>>(out_w, outT, 1024, 512,
      (long long)1024 * 512, (long long)512 * 1024);
  tr_cast<<<dim3(512 / 32, 512 / 32, 2), tb, 0, stream>>>(ff_w1, f1T, 512, 512,
      (long long)512 * 512, (long long)512 * 512);
  tr_cast<<<dim3(512 / 32, 512 / 32, 2), tb, 0, stream>>>(ff_w2, f2T, 512, 512,
      (long long)512 * 512, (long long)512 * 512);
  tr_cast<<<dim3(512 / 32, 512 / 32, 1), tb, 0, stream>>>(enc_w, encT, 512, 512, 0, 0);
  tr_cast<<<dim3(128 / 32, 1024 / 32, 1), tb, 0, stream>>>(cls_w1, c1T, 1024, 128, 0, 0);
  build_mem<<<256, 256, 0, stream>>>(amem, nmem, memc, memTc);

  // ---- conv1d as K=3072 GEMM ----
  gemm<ACT_RELU, false, true, false>(stream, xpad, Wcat, h, conv_b, 1.f, nullptr,
      2048, 512, 3072, 1024, 3072, 512, 1.f,
      8, 8, 0, (long long)2050 * 1024, 0, 0, 0, (long long)2048 * 512);

  // ---- transformer layers ----
  for (int l = 0; l < 2; ++l) {
    ln_kernel<<<16384, 256, 0, stream>>>(h, ln1_g + l * 512, ln1_b + l * 512, xn);
    gemm<ACT_NONE, true, false, false>(stream, xn, qkvT + (long long)l * 2048 * 512, qkvt,
        nullptr, 1.f, nullptr, 16384, 2048, 512, 512, 512, 2048, 1.f,
        1, 1, 0, 0, 0, 0, 0, 0);
    tr_pair<<<dim3(64, 4, 32), tb, 0, stream>>>(qkvt, Vt, 1024);
    tr_pair<<<dim3(64, 4, 32), tb, 0, stream>>>(qkvt, Tt, 1536);
    // o2 = A2 @ t  -> ob cols [h*256+128, h*256+256)
    gemm<ACT_NONE, true, false, false>(stream, A2b, Tt, ob + 128, nullptr, 1.f, nullptr,
        2048, 128, 2048, 2048, 2048, 1024, 1.f,
        32, 4, 0, 0, (long long)4 * 128 * 2048, (long long)128 * 2048,
        (long long)2048 * 1024, 256);
    // o1 via fused flash attention -> ob cols [h*256, h*256+128)
    flash_attn<<<dim3(32, 32), 256, 0, stream>>>(qkvt, Vt, ob, att_scale);
    // h = ob @ out_w[l] + out_b + h
    gemm<ACT_NONE, false, true, true>(stream, ob, outT + (long long)l * 512 * 1024, h,
        out_b + l * 512, 1.f, h, 16384, 512, 1024, 1024, 1024, 512, 1.f,
        1, 1, 0, 0, 0, 0, 0, 0);
    ln_kernel<<<16384, 256, 0, stream>>>(h, ln2_g + l * 512, ln2_b + l * 512, xn);
    gemm<ACT_GELU, true, true, false>(stream, xn, f1T + (long long)l * 512 * 512, ffb,
        ff_b1 + l * 512, 1.f, nullptr, 16384, 512, 512, 512, 512, 512, 1.f,
        1, 1, 0, 0, 0, 0, 0, 0);
    gemm<ACT_NONE, false, true, true>(stream, ffb, f2T + (long long)l * 512 * 512, h,
        ff_b2 + l * 512, 1.f, h, 16384, 512, 512, 512, 512, 512, 1.f,
        1, 1, 0, 0, 0, 0, 0, 0);
  }

  // ---- memory retrieval + classifier ----
  cast_rows<<<(16384 * 512) / 256, 256, 0, stream>>>(h, zb, 512, 1024);
  gemm<ACT_SIGM, true, false, false>(stream, zb, memc, attb, nullptr, 1.f, nullptr,
      16384, 128, 512, 1024, 512, 128, mem_scale, 1, 1, 0, 0, 0, 0, 0, 0);
  gemm<ACT_NONE, true, false, false>(stream, attb, memTc, m1b, nullptr, 1.f, nullptr,
      16384, 512, 128, 128, 128, 512, 1.f, 1, 1, 0, 0, 0, 0, 0, 0);
  gemm<ACT_NONE, true, true, false>(stream, m1b, encT, zb + 512, enc_b, 2.f, nullptr,
      16384, 512, 512, 512, 512, 1024, 1.f, 1, 1, 0, 0, 0, 0, 0, 0);
  gemm<ACT_RELU, true, true, false>(stream, zb, c1T, cls1b, cls_b1, 1.f, nullptr,
      16384, 128, 1024, 1024, 1024, 128, 1.f, 1, 1, 0, 0, 0, 0, 0, 0);
  cls2_kernel<<<4096, 256, 0, stream>>>(cls1b, cls_w2, cls_b2, outp);
}